// Round 1
// baseline (5024.608 us; speedup 1.0000x reference)
//
#include <hip/hip_runtime.h>
#include <hip/hip_bf16.h>
#include <math.h>

// ---------------- helpers ----------------
__device__ __forceinline__ float lrelu(float v) { return v > 0.f ? v : 0.2f * v; }

// order-preserving float<->uint encoding for atomicMax on floats
__device__ __forceinline__ unsigned fenc(float f) {
    unsigned u = __float_as_uint(f);
    return (u & 0x80000000u) ? ~u : (u | 0x80000000u);
}
__device__ __forceinline__ float fdec(unsigned u) {
    return (u & 0x80000000u) ? __uint_as_float(u ^ 0x80000000u) : __uint_as_float(~u);
}
#define NEGINF_ENC 0x007fffffu  // fenc(-inf)

__global__ void k_set_u32(unsigned* __restrict__ p, unsigned v, int n) {
    int i = blockIdx.x * 256 + threadIdx.x;
    if (i < n) p[i] = v;
}

// ---------------- dense matmul: out[N,M] = X[N,128] @ W[128,M] ----------------
// block: 256 threads, 32 rows per block. X tile staged in LDS.
template <int M, int NPT>
__global__ void k_matmul(const float* __restrict__ X, const float* __restrict__ W,
                         float* __restrict__ out, int N) {
    __shared__ float xs[32][128];
    const int tid = threadIdx.x;
    const int row0 = blockIdx.x * 32;
    // stage 32x128 floats = 1024 float4
    for (int i = tid; i < 1024; i += 256) {
        int r = i >> 5, c4 = i & 31;
        int gr = row0 + r;
        float4 v = make_float4(0.f, 0.f, 0.f, 0.f);
        if (gr < N) v = ((const float4*)X)[gr * 32 + c4];
        ((float4*)&xs[r][0])[c4] = v;
    }
    __syncthreads();
    const int c = tid % M;
    const int r0 = tid / M;
    const int RSTEP = 256 / M;
    float acc[NPT];
#pragma unroll
    for (int i = 0; i < NPT; i++) acc[i] = 0.f;
    for (int k = 0; k < 128; k++) {
        float w = W[k * M + c];
#pragma unroll
        for (int i = 0; i < NPT; i++) acc[i] += xs[r0 + i * RSTEP][k] * w;
    }
#pragma unroll
    for (int i = 0; i < NPT; i++) {
        int gr = row0 + r0 + i * RSTEP;
        if (gr < N) out[gr * M + c] = acc[i];
    }
}

// ---------------- el/er: el[n,h] = sum_d feat[n,h,d]*al[h,d] ----------------
template <int H, int D>
__global__ void k_eler(const float* __restrict__ feat, const float* __restrict__ al,
                       const float* __restrict__ ar, float* __restrict__ el,
                       float* __restrict__ er, int N) {
    __shared__ float sal[H * D], sar[H * D];
    for (int i = threadIdx.x; i < H * D; i += 256) { sal[i] = al[i]; sar[i] = ar[i]; }
    __syncthreads();
    int n = blockIdx.x * 256 + threadIdx.x;
    if (n >= N) return;
    const float4* f4 = (const float4*)(feat + (size_t)n * H * D);
    float accl[H], accr[H];
#pragma unroll
    for (int h = 0; h < H; h++) { accl[h] = 0.f; accr[h] = 0.f; }
#pragma unroll
    for (int q = 0; q < H * D / 4; q++) {
        float4 v = f4[q];
        const int h = (q * 4) / D;
        const int d = (q * 4) % D;
        accl[h] += v.x * sal[h * D + d] + v.y * sal[h * D + d + 1] +
                   v.z * sal[h * D + d + 2] + v.w * sal[h * D + d + 3];
        accr[h] += v.x * sar[h * D + d] + v.y * sar[h * D + d + 1] +
                   v.z * sar[h * D + d + 2] + v.w * sar[h * D + d + 3];
    }
#pragma unroll
    for (int h = 0; h < H; h++) { el[n * H + h] = accl[h]; er[n * H + h] = accr[h]; }
}

// ---------------- edge pass 1: segment max (encoded atomicMax) ----------------
template <int H>
__global__ void k_edge_max(const int* __restrict__ src, const int* __restrict__ dst,
                           const float* __restrict__ el, const float* __restrict__ er,
                           unsigned* __restrict__ m, int E) {
    int e = blockIdx.x * 256 + threadIdx.x;
    if (e >= E) return;
    int s = src[e], d = dst[e];
#pragma unroll
    for (int h = 0; h < H; h++) {
        float v = lrelu(el[s * H + h] + er[d * H + h]);
        atomicMax(&m[d * H + h], fenc(v));
    }
}

// ---------------- edge pass 2: softmax denominator ----------------
template <int H>
__global__ void k_edge_sum(const int* __restrict__ src, const int* __restrict__ dst,
                           const float* __restrict__ el, const float* __restrict__ er,
                           const unsigned* __restrict__ m, float* __restrict__ sden, int E) {
    int e = blockIdx.x * 256 + threadIdx.x;
    if (e >= E) return;
    int s = src[e], d = dst[e];
#pragma unroll
    for (int h = 0; h < H; h++) {
        float v = lrelu(el[s * H + h] + er[d * H + h]);
        float ex = __expf(v - fdec(m[d * H + h]));
        atomicAdd(&sden[d * H + h], ex);
    }
}

// ---------------- edge pass 3: alpha * feat[src] scatter-add ----------------
template <int H, int D>
__global__ void k_edge_msg(const int* __restrict__ src, const int* __restrict__ dst,
                           const float* __restrict__ el, const float* __restrict__ er,
                           const unsigned* __restrict__ m, const float* __restrict__ sden,
                           const float* __restrict__ feat, float* __restrict__ acc, int E) {
    const int LPE = H * D / 4;  // lanes per edge (float4 each)
    int gid = blockIdx.x * 256 + threadIdx.x;
    int e = gid / LPE;
    int lane = gid % LPE;
    if (e >= E) return;
    int s = src[e], d = dst[e];
    int h = (lane * 4) / D;
    float v = lrelu(el[s * H + h] + er[d * H + h]);
    float alpha = __expf(v - fdec(m[d * H + h])) / sden[d * H + h];
    float4 f = ((const float4*)(feat + (size_t)s * H * D))[lane];
    float* o = acc + (size_t)d * H * D + lane * 4;
    atomicAdd(o + 0, alpha * f.x);
    atomicAdd(o + 1, alpha * f.y);
    atomicAdd(o + 2, alpha * f.z);
    atomicAdd(o + 3, alpha * f.w);
}

// ---------------- finalizers ----------------
__global__ void k_fin1(float* __restrict__ h1, const float* __restrict__ b1, int N) {
    int i = blockIdx.x * 256 + threadIdx.x;
    if (i >= N * 128) return;
    int c = i & 127;
    float v = h1[i] + b1[c] + b1[128 + c];
    h1[i] = v > 0.f ? v : expm1f(v);
}
__global__ void k_fin2(float* __restrict__ out, const float* __restrict__ b2, int N) {
    int i = blockIdx.x * 256 + threadIdx.x;
    if (i >= N * 64) return;
    int c = i & 63;
    out[i] = out[i] + b2[c] + b2[64 + c];
}

// ---------------- launch ----------------
extern "C" void kernel_launch(void* const* d_in, const int* in_sizes, int n_in,
                              void* d_out, int out_size, void* d_ws, size_t ws_size,
                              hipStream_t stream) {
    const float* x   = (const float*)d_in[0];
    const float* W1  = (const float*)d_in[1];
    const float* al1 = (const float*)d_in[2];
    const float* ar1 = (const float*)d_in[3];
    const float* b1  = (const float*)d_in[4];
    const float* W2  = (const float*)d_in[5];
    const float* al2 = (const float*)d_in[6];
    const float* ar2 = (const float*)d_in[7];
    const float* b2  = (const float*)d_in[8];
    const int* src   = (const int*)d_in[9];
    const int* dst   = (const int*)d_in[10];

    const int N = in_sizes[0] / 128;
    const int E = in_sizes[9] / 2;
    float* out = (float*)d_out;

    char* w = (char*)d_ws;
    float* h1      = (float*)w; w += (size_t)N * 128 * 4;
    float* feat    = (float*)w; w += (size_t)N * 128 * 4;
    float* el      = (float*)w; w += (size_t)N * 4 * 4;
    float* er      = (float*)w; w += (size_t)N * 4 * 4;
    unsigned* m    = (unsigned*)w; w += (size_t)N * 4 * 4;
    float* sden    = (float*)w; w += (size_t)N * 4 * 4;

    auto cdiv = [](long long a, long long b) { return (int)((a + b - 1) / b); };

    k_set_u32<<<cdiv((long long)N * 128, 256), 256, 0, stream>>>((unsigned*)h1, 0u, N * 128);
    k_set_u32<<<cdiv((long long)N * 64, 256), 256, 0, stream>>>((unsigned*)out, 0u, N * 64);

    // ---- layer 1: H=4, D=32, M=128 ----
    for (int r = 0; r < 2; r++) {
        const int* sr = src + (size_t)r * E;
        const int* dr = dst + (size_t)r * E;
        k_matmul<128, 16><<<cdiv(N, 32), 256, 0, stream>>>(x, W1 + (size_t)r * 128 * 128, feat, N);
        k_eler<4, 32><<<cdiv(N, 256), 256, 0, stream>>>(feat, al1 + r * 128, ar1 + r * 128, el, er, N);
        k_set_u32<<<cdiv((long long)N * 4, 256), 256, 0, stream>>>(m, NEGINF_ENC, N * 4);
        k_set_u32<<<cdiv((long long)N * 4, 256), 256, 0, stream>>>((unsigned*)sden, 0u, N * 4);
        k_edge_max<4><<<cdiv(E, 256), 256, 0, stream>>>(sr, dr, el, er, m, E);
        k_edge_sum<4><<<cdiv(E, 256), 256, 0, stream>>>(sr, dr, el, er, m, sden, E);
        k_edge_msg<4, 32><<<cdiv((long long)E * 32, 256), 256, 0, stream>>>(sr, dr, el, er, m, sden, feat, h1, E);
    }
    k_fin1<<<cdiv((long long)N * 128, 256), 256, 0, stream>>>(h1, b1, N);

    // ---- layer 2: H=1, D=64, M=64 ----
    for (int r = 0; r < 2; r++) {
        const int* sr = src + (size_t)r * E;
        const int* dr = dst + (size_t)r * E;
        k_matmul<64, 8><<<cdiv(N, 32), 256, 0, stream>>>(h1, W2 + (size_t)r * 128 * 64, feat, N);
        k_eler<1, 64><<<cdiv(N, 256), 256, 0, stream>>>(feat, al2 + r * 64, ar2 + r * 64, el, er, N);
        k_set_u32<<<cdiv(N, 256), 256, 0, stream>>>(m, NEGINF_ENC, N);
        k_set_u32<<<cdiv(N, 256), 256, 0, stream>>>((unsigned*)sden, 0u, N);
        k_edge_max<1><<<cdiv(E, 256), 256, 0, stream>>>(sr, dr, el, er, m, E);
        k_edge_sum<1><<<cdiv(E, 256), 256, 0, stream>>>(sr, dr, el, er, m, sden, E);
        k_edge_msg<1, 64><<<cdiv((long long)E * 16, 256), 256, 0, stream>>>(sr, dr, el, er, m, sden, feat, out, E);
    }
    k_fin2<<<cdiv((long long)N * 64, 256), 256, 0, stream>>>(out, b2, N);
}

// Round 2
// 662.061 us; speedup vs baseline: 7.5893x; 7.5893x over previous
//
#include <hip/hip_runtime.h>
#include <hip/hip_bf16.h>
#include <math.h>

// ---------------- helpers ----------------
__global__ void k_set_u32(unsigned* __restrict__ p, unsigned v, int n) {
    int i = blockIdx.x * 256 + threadIdx.x;
    if (i < n) p[i] = v;
}

// ---------------- CSR build (dst-indexed), shared by both layers ----------------
__global__ void k_hist(const int* __restrict__ dst, unsigned* __restrict__ cnt, int E, int N) {
    int i = blockIdx.x * 256 + threadIdx.x;
    if (i >= 2 * E) return;
    int r = i / E;
    atomicAdd(&cnt[(size_t)r * N + dst[i]], 1u);
}

// one block per relation; exclusive scan of cnt[N] -> off[N+1]
__global__ void k_scan(const unsigned* __restrict__ cnt, unsigned* __restrict__ off, int n) {
    cnt += (size_t)blockIdx.x * n;
    off += (size_t)blockIdx.x * (n + 1);
    __shared__ unsigned tmp[1024];
    __shared__ unsigned s_carry;
    if (threadIdx.x == 0) s_carry = 0;
    __syncthreads();
    for (int base = 0; base < n; base += 1024) {
        int i = base + (int)threadIdx.x;
        unsigned v = (i < n) ? cnt[i] : 0u;
        tmp[threadIdx.x] = v;
        __syncthreads();
        for (int st = 1; st < 1024; st <<= 1) {
            unsigned t = (threadIdx.x >= (unsigned)st) ? tmp[threadIdx.x - st] : 0u;
            __syncthreads();
            tmp[threadIdx.x] += t;
            __syncthreads();
        }
        if (i < n) off[i] = s_carry + tmp[threadIdx.x] - v;
        __syncthreads();
        if (threadIdx.x == 1023) s_carry += tmp[1023];
        __syncthreads();
    }
    if (threadIdx.x == 0) off[n] = s_carry;
}

__global__ void k_scatter(const int* __restrict__ src, const int* __restrict__ dst,
                          const unsigned* __restrict__ off, unsigned* __restrict__ cur,
                          int* __restrict__ csr_src, int E, int N) {
    int i = blockIdx.x * 256 + threadIdx.x;
    if (i >= 2 * E) return;
    int r = i / E;
    int d = dst[i];
    unsigned pos = atomicAdd(&cur[(size_t)r * N + d], 1u);
    csr_src[(size_t)r * E + off[(size_t)r * (N + 1) + d] + pos] = src[i];
}

// ---------------- dense matmul: out[N,M] = X[N,128] @ W[128,M] ----------------
template <int M, int NPT>
__global__ void k_matmul(const float* __restrict__ X, const float* __restrict__ W,
                         float* __restrict__ out, int N) {
    __shared__ float xs[32][128];
    const int tid = threadIdx.x;
    const int row0 = blockIdx.x * 32;
    for (int i = tid; i < 1024; i += 256) {
        int r = i >> 5, c4 = i & 31;
        int gr = row0 + r;
        float4 v = make_float4(0.f, 0.f, 0.f, 0.f);
        if (gr < N) v = ((const float4*)X)[gr * 32 + c4];
        ((float4*)&xs[r][0])[c4] = v;
    }
    __syncthreads();
    const int c = tid % M;
    const int r0 = tid / M;
    const int RSTEP = 256 / M;
    float acc[NPT];
#pragma unroll
    for (int i = 0; i < NPT; i++) acc[i] = 0.f;
    for (int k = 0; k < 128; k++) {
        float w = W[k * M + c];
#pragma unroll
        for (int i = 0; i < NPT; i++) acc[i] += xs[r0 + i * RSTEP][k] * w;
    }
#pragma unroll
    for (int i = 0; i < NPT; i++) {
        int gr = row0 + r0 + i * RSTEP;
        if (gr < N) out[gr * M + c] = acc[i];
    }
}

// ---------------- el/er: el[n,h] = sum_d feat[n,h,d]*al[h,d] ----------------
template <int H, int D>
__global__ void k_eler(const float* __restrict__ feat, const float* __restrict__ al,
                       const float* __restrict__ ar, float* __restrict__ el,
                       float* __restrict__ er, int N) {
    __shared__ float sal[H * D], sar[H * D];
    for (int i = threadIdx.x; i < H * D; i += 256) { sal[i] = al[i]; sar[i] = ar[i]; }
    __syncthreads();
    int n = blockIdx.x * 256 + threadIdx.x;
    if (n >= N) return;
    const float4* f4 = (const float4*)(feat + (size_t)n * H * D);
    float accl[H], accr[H];
#pragma unroll
    for (int h = 0; h < H; h++) { accl[h] = 0.f; accr[h] = 0.f; }
#pragma unroll
    for (int q = 0; q < H * D / 4; q++) {
        float4 v = f4[q];
        const int h = (q * 4) / D;
        const int d = (q * 4) % D;
        accl[h] += v.x * sal[h * D + d] + v.y * sal[h * D + d + 1] +
                   v.z * sal[h * D + d + 2] + v.w * sal[h * D + d + 3];
        accr[h] += v.x * sar[h * D + d] + v.y * sar[h * D + d + 1] +
                   v.z * sar[h * D + d + 2] + v.w * sar[h * D + d + 3];
    }
#pragma unroll
    for (int h = 0; h < H; h++) { el[n * H + h] = accl[h]; er[n * H + h] = accr[h]; }
}

// ---------------- fused per-node GAT: online softmax + gather + bias/act ----------------
// one wave (64 lanes) per node; lane owns F = H*D/64 consecutive output columns.
template <int H, int D>
__global__ __launch_bounds__(256) void k_node_gat(
    const unsigned* __restrict__ off,       // [2][N+1]
    const int* __restrict__ csr_src,        // [2][E]
    const float* __restrict__ el,           // [2][N*H]
    const float* __restrict__ er,           // [2][N*H]
    const float* __restrict__ feat0,        // [N,H*D] relation 0
    const float* __restrict__ feat1,        // [N,H*D] relation 1
    const float* __restrict__ bias,         // [2][H*D]
    float* __restrict__ outp,               // [N,H*D]
    int N, int E, int elu_flag) {
    constexpr int HD = H * D;
    constexpr int F = HD / 64;
    int wid = (blockIdx.x * 256 + threadIdx.x) >> 6;
    int lane = threadIdx.x & 63;
    if (wid >= N) return;
    const int n = wid;
    const int c0 = lane * F;
    const int h = c0 / D;

    float res[F];
#pragma unroll
    for (int f = 0; f < F; f++) res[f] = 0.f;

    for (int r = 0; r < 2; r++) {
        const float* feat = r ? feat1 : feat0;
        const float* elr = el + (size_t)r * N * H;
        const float ern = er[(size_t)r * N * H + (size_t)n * H + h];
        const unsigned* offr = off + (size_t)r * (N + 1);
        const int* srcs = csr_src + (size_t)r * E;
        const unsigned o0 = offr[n], o1 = offr[n + 1];

        float m = -1e30f, s = 0.f;
        float acc[F];
#pragma unroll
        for (int f = 0; f < F; f++) acc[f] = 0.f;

        for (unsigned base = o0; base < o1; base += 64) {
            int cnt = (int)min(64u, o1 - base);
            int sid = (base + (unsigned)lane < o1) ? srcs[base + lane] : 0;
            for (int j = 0; j < cnt; j++) {
                int sv = __shfl(sid, j);
                float v = elr[(size_t)sv * H + h] + ern;
                v = v > 0.f ? v : 0.2f * v;           // leaky_relu
                float nm = fmaxf(m, v);
                float cfac = __expf(m - nm);
                float p = __expf(v - nm);
                m = nm;
                s = s * cfac + p;
                if (F == 2) {
                    float2 fv = ((const float2*)(feat + (size_t)sv * HD))[lane];
                    acc[0] = acc[0] * cfac + p * fv.x;
                    acc[1] = acc[1] * cfac + p * fv.y;
                } else {
                    float fv = feat[(size_t)sv * HD + lane];
                    acc[0] = acc[0] * cfac + p * fv;
                }
            }
        }
        if (s > 0.f) {
            float inv = 1.f / s;
#pragma unroll
            for (int f = 0; f < F; f++) res[f] += acc[f] * inv;
        }
    }
#pragma unroll
    for (int f = 0; f < F; f++) {
        int c = c0 + f;
        float v = res[f] + bias[c] + bias[HD + c];
        if (elu_flag) v = v > 0.f ? v : expm1f(v);    // elu
        outp[(size_t)n * HD + c] = v;
    }
}

// ---------------- launch ----------------
extern "C" void kernel_launch(void* const* d_in, const int* in_sizes, int n_in,
                              void* d_out, int out_size, void* d_ws, size_t ws_size,
                              hipStream_t stream) {
    const float* x   = (const float*)d_in[0];
    const float* W1  = (const float*)d_in[1];
    const float* al1 = (const float*)d_in[2];
    const float* ar1 = (const float*)d_in[3];
    const float* b1  = (const float*)d_in[4];
    const float* W2  = (const float*)d_in[5];
    const float* al2 = (const float*)d_in[6];
    const float* ar2 = (const float*)d_in[7];
    const float* b2  = (const float*)d_in[8];
    const int* src   = (const int*)d_in[9];
    const int* dst   = (const int*)d_in[10];

    const int N = in_sizes[0] / 128;
    const int E = in_sizes[9] / 2;
    float* out = (float*)d_out;

    char* w = (char*)d_ws;
    float* featA   = (float*)w; w += (size_t)N * 128 * 4;
    float* featB   = (float*)w; w += (size_t)N * 128 * 4;
    float* h1      = (float*)w; w += (size_t)N * 128 * 4;
    float* el      = (float*)w; w += (size_t)2 * N * 4 * 4;
    float* er      = (float*)w; w += (size_t)2 * N * 4 * 4;
    unsigned* cnt  = (unsigned*)w; w += (size_t)2 * N * 4;      // also reused as cursor
    unsigned* off  = (unsigned*)w; w += (size_t)2 * (N + 1) * 4;
    int* csr_src   = (int*)w; w += (size_t)2 * E * 4;

    auto cdiv = [](long long a, long long b) { return (int)((a + b - 1) / b); };

    // ---- CSR build (once; shared by both layers) ----
    k_set_u32<<<cdiv(2LL * N, 256), 256, 0, stream>>>(cnt, 0u, 2 * N);
    k_hist<<<cdiv(2LL * E, 256), 256, 0, stream>>>(dst, cnt, E, N);
    k_scan<<<2, 1024, 0, stream>>>(cnt, off, N);
    k_set_u32<<<cdiv(2LL * N, 256), 256, 0, stream>>>(cnt, 0u, 2 * N);
    k_scatter<<<cdiv(2LL * E, 256), 256, 0, stream>>>(src, dst, off, cnt, csr_src, E, N);

    // ---- layer 1: H=4, D=32 ----
    for (int r = 0; r < 2; r++) {
        float* feat = r ? featB : featA;
        k_matmul<128, 16><<<cdiv(N, 32), 256, 0, stream>>>(x, W1 + (size_t)r * 128 * 128, feat, N);
        k_eler<4, 32><<<cdiv(N, 256), 256, 0, stream>>>(feat, al1 + r * 128, ar1 + r * 128,
                                                        el + (size_t)r * N * 4, er + (size_t)r * N * 4, N);
    }
    k_node_gat<4, 32><<<cdiv(N, 4), 256, 0, stream>>>(off, csr_src, el, er, featA, featB, b1, h1, N, E, 1);

    // ---- layer 2: H=1, D=64 ----
    for (int r = 0; r < 2; r++) {
        float* feat = r ? featB : featA;
        k_matmul<64, 8><<<cdiv(N, 32), 256, 0, stream>>>(h1, W2 + (size_t)r * 128 * 64, feat, N);
        k_eler<1, 64><<<cdiv(N, 256), 256, 0, stream>>>(feat, al2 + r * 64, ar2 + r * 64,
                                                        el + (size_t)r * N, er + (size_t)r * N, N);
    }
    k_node_gat<1, 64><<<cdiv(N, 4), 256, 0, stream>>>(off, csr_src, el, er, featA, featB, b2, out, N, E, 0);
}

// Round 3
// 552.570 us; speedup vs baseline: 9.0932x; 1.1981x over previous
//
#include <hip/hip_runtime.h>
#include <hip/hip_bf16.h>
#include <math.h>

__device__ __forceinline__ float b2f(unsigned short u) {
    return __uint_as_float(((unsigned)u) << 16);
}

__global__ void k_set_u32(unsigned* __restrict__ p, unsigned v, int n) {
    int i = blockIdx.x * 256 + threadIdx.x;
    if (i < n) p[i] = v;
}

// ---------------- CSR build (dst-indexed), shared by both layers ----------------
__global__ void k_hist(const int* __restrict__ dst, unsigned* __restrict__ cnt, int E, int N) {
    int i = blockIdx.x * 256 + threadIdx.x;
    if (i >= 2 * E) return;
    int r = i / E;
    atomicAdd(&cnt[(size_t)r * N + dst[i]], 1u);
}

// one block per relation; exclusive scan of cnt[N] -> off[N+1]
__global__ void k_scan(const unsigned* __restrict__ cnt, unsigned* __restrict__ off, int n) {
    cnt += (size_t)blockIdx.x * n;
    off += (size_t)blockIdx.x * (n + 1);
    __shared__ unsigned tmp[1024];
    __shared__ unsigned s_carry;
    if (threadIdx.x == 0) s_carry = 0;
    __syncthreads();
    for (int base = 0; base < n; base += 1024) {
        int i = base + (int)threadIdx.x;
        unsigned v = (i < n) ? cnt[i] : 0u;
        tmp[threadIdx.x] = v;
        __syncthreads();
        for (int st = 1; st < 1024; st <<= 1) {
            unsigned t = (threadIdx.x >= (unsigned)st) ? tmp[threadIdx.x - st] : 0u;
            __syncthreads();
            tmp[threadIdx.x] += t;
            __syncthreads();
        }
        if (i < n) off[i] = s_carry + tmp[threadIdx.x] - v;
        __syncthreads();
        if (threadIdx.x == 1023) s_carry += tmp[1023];
        __syncthreads();
    }
    if (threadIdx.x == 0) off[n] = s_carry;
}

__global__ void k_scatter(const int* __restrict__ src, const int* __restrict__ dst,
                          const unsigned* __restrict__ off, unsigned* __restrict__ cur,
                          int* __restrict__ csr_src, int E, int N) {
    int i = blockIdx.x * 256 + threadIdx.x;
    if (i >= 2 * E) return;
    int r = i / E;
    int d = dst[i];
    unsigned pos = atomicAdd(&cur[(size_t)r * N + d], 1u);
    csr_src[(size_t)r * E + off[(size_t)r * (N + 1) + d] + pos] = src[i];
}

// ---------------- dense matmul: out[N,M](bf16) = X[N,128](f32) @ W[128,M](f32) ----------------
template <int M, int NPT>
__global__ void k_matmul(const float* __restrict__ X, const float* __restrict__ W,
                         __hip_bfloat16* __restrict__ out, int N) {
    __shared__ float xs[32][128];
    const int tid = threadIdx.x;
    const int row0 = blockIdx.x * 32;
    for (int i = tid; i < 1024; i += 256) {
        int r = i >> 5, c4 = i & 31;
        int gr = row0 + r;
        float4 v = make_float4(0.f, 0.f, 0.f, 0.f);
        if (gr < N) v = ((const float4*)X)[gr * 32 + c4];
        ((float4*)&xs[r][0])[c4] = v;
    }
    __syncthreads();
    const int c = tid % M;
    const int r0 = tid / M;
    const int RSTEP = 256 / M;
    float acc[NPT];
#pragma unroll
    for (int i = 0; i < NPT; i++) acc[i] = 0.f;
    for (int k4 = 0; k4 < 32; k4++) {
        const float* wp = W + (size_t)k4 * 4 * M + c;
        float w0 = wp[0], w1 = wp[M], w2 = wp[2 * M], w3 = wp[3 * M];
#pragma unroll
        for (int i = 0; i < NPT; i++) {
            float4 xv = *(const float4*)&xs[r0 + i * RSTEP][k4 * 4];
            acc[i] += xv.x * w0 + xv.y * w1 + xv.z * w2 + xv.w * w3;
        }
    }
#pragma unroll
    for (int i = 0; i < NPT; i++) {
        int gr = row0 + r0 + i * RSTEP;
        if (gr < N) out[(size_t)gr * M + c] = __float2bfloat16(acc[i]);
    }
}

// ---------------- el/er from bf16 feat ----------------
template <int H, int D>
__global__ void k_eler(const __hip_bfloat16* __restrict__ feat, const float* __restrict__ al,
                       const float* __restrict__ ar, float* __restrict__ el,
                       float* __restrict__ er, int N) {
    constexpr int HD = H * D;
    __shared__ float sal[HD], sar[HD];
    for (int i = threadIdx.x; i < HD; i += 256) { sal[i] = al[i]; sar[i] = ar[i]; }
    __syncthreads();
    int n = blockIdx.x * 256 + threadIdx.x;
    if (n >= N) return;
    const uint4* f4 = (const uint4*)(feat + (size_t)n * HD);
    float accl[H], accr[H];
#pragma unroll
    for (int h = 0; h < H; h++) { accl[h] = 0.f; accr[h] = 0.f; }
#pragma unroll
    for (int q = 0; q < HD / 8; q++) {
        uint4 u = f4[q];
        unsigned uu[4] = {u.x, u.y, u.z, u.w};
#pragma unroll
        for (int t = 0; t < 4; t++) {
            int d0 = q * 8 + t * 2;
            int h = d0 / D;
            float f0 = b2f((unsigned short)(uu[t] & 0xffff));
            float f1 = b2f((unsigned short)(uu[t] >> 16));
            accl[h] += f0 * sal[d0] + f1 * sal[d0 + 1];
            accr[h] += f0 * sar[d0] + f1 * sar[d0 + 1];
        }
    }
#pragma unroll
    for (int h = 0; h < H; h++) { el[(size_t)n * H + h] = accl[h]; er[(size_t)n * H + h] = accr[h]; }
}

// ---------------- fused per-node GAT: no-max softmax, two-phase, bf16 gather ----------------
// one wave per node; lane owns F = H*D/64 consecutive output columns.
template <int H, int D>
__global__ __launch_bounds__(256) void k_node_gat(
    const unsigned* __restrict__ off,       // [2][N+1]
    const int* __restrict__ csr_src,        // [2][E]
    const float* __restrict__ el,           // [2][N*H]
    const float* __restrict__ er,           // [2][N*H]
    const __hip_bfloat16* __restrict__ feat0,
    const __hip_bfloat16* __restrict__ feat1,
    const float* __restrict__ bias,         // [2][H*D]
    float* __restrict__ outp,               // [N,H*D]
    int N, int E, int elu_flag) {
    constexpr int HD = H * D;
    constexpr int F = HD / 64;
    __shared__ float s_w[4][H * 64];
    __shared__ int s_sid[4][64];
    const int wslot = threadIdx.x >> 6;
    const int lane = threadIdx.x & 63;
    const int n = (blockIdx.x * 256 + threadIdx.x) >> 6;
    if (n >= N) return;
    const int c0 = lane * F;
    const int h = c0 / D;

    float res[F];
#pragma unroll
    for (int f = 0; f < F; f++) res[f] = 0.f;

    for (int r = 0; r < 2; r++) {
        const __hip_bfloat16* feat = r ? feat1 : feat0;
        const float* elr = el + (size_t)r * N * H;
        const float* ernp = er + (size_t)r * N * H + (size_t)n * H;
        float ern[H];
#pragma unroll
        for (int hh = 0; hh < H; hh++) ern[hh] = ernp[hh];
        const unsigned* offr = off + (size_t)r * (N + 1);
        const int* srcs = csr_src + (size_t)r * E;
        const unsigned o0 = offr[n], o1 = offr[n + 1];

        float ssum[H];
#pragma unroll
        for (int hh = 0; hh < H; hh++) ssum[hh] = 0.f;
        float acc[F];
#pragma unroll
        for (int f = 0; f < F; f++) acc[f] = 0.f;

        for (unsigned base = o0; base < o1; base += 64) {
            const int cnt = (int)min(64u, o1 - base);
            // phase A: edge-parallel score -> exp -> LDS
            if (lane < cnt) {
                int sv = srcs[base + lane];
                s_sid[wslot][lane] = sv;
                if (H == 4) {
                    float4 e4 = *(const float4*)(elr + (size_t)sv * 4);
                    float v0 = e4.x + ern[0]; v0 = v0 > 0.f ? v0 : 0.2f * v0;
                    float v1 = e4.y + ern[1]; v1 = v1 > 0.f ? v1 : 0.2f * v1;
                    float v2 = e4.z + ern[2]; v2 = v2 > 0.f ? v2 : 0.2f * v2;
                    float v3 = e4.w + ern[3]; v3 = v3 > 0.f ? v3 : 0.2f * v3;
                    float w0 = __expf(v0), w1 = __expf(v1), w2 = __expf(v2), w3 = __expf(v3);
                    s_w[wslot][0 * 64 + lane] = w0; ssum[0] += w0;
                    s_w[wslot][1 * 64 + lane] = w1; ssum[1] += w1;
                    s_w[wslot][2 * 64 + lane] = w2; ssum[2] += w2;
                    s_w[wslot][3 * 64 + lane] = w3; ssum[3] += w3;
                } else {
                    float v = elr[sv] + ern[0]; v = v > 0.f ? v : 0.2f * v;
                    float w0 = __expf(v);
                    s_w[wslot][lane] = w0; ssum[0] += w0;
                }
            }
            asm volatile("s_waitcnt lgkmcnt(0)" ::: "memory");
            // phase B: serial gather + FMA (same-wave LDS is in-order; no cross-wave sharing)
#pragma unroll 4
            for (int j = 0; j < cnt; j++) {
                int sv = s_sid[wslot][j];
                float wv = s_w[wslot][h * 64 + j];
                if (F == 2) {
                    unsigned u = ((const unsigned*)(feat + (size_t)sv * HD))[lane];
                    acc[0] += wv * b2f((unsigned short)(u & 0xffff));
                    acc[1] += wv * b2f((unsigned short)(u >> 16));
                } else {
                    acc[0] += wv * b2f(((const unsigned short*)(feat + (size_t)sv * HD))[lane]);
                }
            }
        }
        // reduce denominator across lanes
#pragma unroll
        for (int hh = 0; hh < H; hh++) {
            float v = ssum[hh];
#pragma unroll
            for (int o = 32; o > 0; o >>= 1) v += __shfl_xor(v, o);
            ssum[hh] = v;
        }
        float s = ssum[h];
        if (s > 0.f) {
            float inv = 1.f / s;
#pragma unroll
            for (int f = 0; f < F; f++) res[f] += acc[f] * inv;
        }
    }
#pragma unroll
    for (int f = 0; f < F; f++) {
        int c = c0 + f;
        float v = res[f] + bias[c] + bias[HD + c];
        if (elu_flag) v = v > 0.f ? v : expm1f(v);
        outp[(size_t)n * HD + c] = v;
    }
}

// ---------------- launch ----------------
extern "C" void kernel_launch(void* const* d_in, const int* in_sizes, int n_in,
                              void* d_out, int out_size, void* d_ws, size_t ws_size,
                              hipStream_t stream) {
    const float* x   = (const float*)d_in[0];
    const float* W1  = (const float*)d_in[1];
    const float* al1 = (const float*)d_in[2];
    const float* ar1 = (const float*)d_in[3];
    const float* b1  = (const float*)d_in[4];
    const float* W2  = (const float*)d_in[5];
    const float* al2 = (const float*)d_in[6];
    const float* ar2 = (const float*)d_in[7];
    const float* b2  = (const float*)d_in[8];
    const int* src   = (const int*)d_in[9];
    const int* dst   = (const int*)d_in[10];

    const int N = in_sizes[0] / 128;
    const int E = in_sizes[9] / 2;
    float* out = (float*)d_out;

    char* w = (char*)d_ws;
    __hip_bfloat16* featA = (__hip_bfloat16*)w; w += (size_t)N * 128 * 2;
    __hip_bfloat16* featB = (__hip_bfloat16*)w; w += (size_t)N * 128 * 2;
    float* h1      = (float*)w; w += (size_t)N * 128 * 4;
    float* el      = (float*)w; w += (size_t)2 * N * 4 * 4;
    float* er      = (float*)w; w += (size_t)2 * N * 4 * 4;
    unsigned* cnt  = (unsigned*)w; w += (size_t)2 * N * 4;
    unsigned* off  = (unsigned*)w; w += (size_t)2 * (N + 1) * 4;
    int* csr_src   = (int*)w; w += (size_t)2 * E * 4;

    auto cdiv = [](long long a, long long b) { return (int)((a + b - 1) / b); };

    // ---- CSR build (once; shared by both layers) ----
    k_set_u32<<<cdiv(2LL * N, 256), 256, 0, stream>>>(cnt, 0u, 2 * N);
    k_hist<<<cdiv(2LL * E, 256), 256, 0, stream>>>(dst, cnt, E, N);
    k_scan<<<2, 1024, 0, stream>>>(cnt, off, N);
    k_set_u32<<<cdiv(2LL * N, 256), 256, 0, stream>>>(cnt, 0u, 2 * N);
    k_scatter<<<cdiv(2LL * E, 256), 256, 0, stream>>>(src, dst, off, cnt, csr_src, E, N);

    // ---- layer 1: H=4, D=32 ----
    for (int r = 0; r < 2; r++) {
        __hip_bfloat16* feat = r ? featB : featA;
        k_matmul<128, 16><<<cdiv(N, 32), 256, 0, stream>>>(x, W1 + (size_t)r * 128 * 128, feat, N);
        k_eler<4, 32><<<cdiv(N, 256), 256, 0, stream>>>(feat, al1 + r * 128, ar1 + r * 128,
                                                        el + (size_t)r * N * 4, er + (size_t)r * N * 4, N);
    }
    k_node_gat<4, 32><<<cdiv(N, 4), 256, 0, stream>>>(off, csr_src, el, er, featA, featB, b1, h1, N, E, 1);

    // ---- layer 2: H=1, D=64 ----
    for (int r = 0; r < 2; r++) {
        __hip_bfloat16* feat = r ? featB : featA;
        k_matmul<64, 8><<<cdiv(N, 32), 256, 0, stream>>>(h1, W2 + (size_t)r * 128 * 64, feat, N);
        k_eler<1, 64><<<cdiv(N, 256), 256, 0, stream>>>(feat, al2 + r * 64, ar2 + r * 64,
                                                        el + (size_t)r * N, er + (size_t)r * N, N);
    }
    k_node_gat<1, 64><<<cdiv(N, 4), 256, 0, stream>>>(off, csr_src, el, er, featA, featB, b2, out, N, E, 0);
}

// Round 4
// 348.894 us; speedup vs baseline: 14.4015x; 1.5838x over previous
//
#include <hip/hip_runtime.h>
#include <hip/hip_bf16.h>
#include <math.h>

using bf16x8 = __attribute__((ext_vector_type(8))) short;
using f32x4  = __attribute__((ext_vector_type(4))) float;

__device__ __forceinline__ float b2f(unsigned short u) {
    return __uint_as_float(((unsigned)u) << 16);
}
__device__ __forceinline__ unsigned short f2b(float f) {
    unsigned u = __float_as_uint(f);
    return (unsigned short)((u + 0x7fff + ((u >> 16) & 1)) >> 16);
}

__global__ void k_set_u32(unsigned* __restrict__ p, unsigned v, int n) {
    int i = blockIdx.x * 256 + threadIdx.x;
    if (i < n) p[i] = v;
}

// ---------------- bf16 prep ----------------
__global__ void k_prepx(const float* __restrict__ x, unsigned short* __restrict__ xb, int n8) {
    int i = blockIdx.x * 256 + threadIdx.x;
    if (i >= n8) return;
    float4 a = ((const float4*)x)[i * 2], b = ((const float4*)x)[i * 2 + 1];
    uint4 o;
    o.x = f2b(a.x) | ((unsigned)f2b(a.y) << 16);
    o.y = f2b(a.z) | ((unsigned)f2b(a.w) << 16);
    o.z = f2b(b.x) | ((unsigned)f2b(b.y) << 16);
    o.w = f2b(b.z) | ((unsigned)f2b(b.w) << 16);
    ((uint4*)xb)[i] = o;
}

// Wt1[r][c][k] = W1[r][k][c]  (2x128x128);  Wt2[r][c][k] = W2[r][k][c] (2x64x128)
__global__ void k_prepw(const float* __restrict__ W1, const float* __restrict__ W2,
                        unsigned short* __restrict__ wt1, unsigned short* __restrict__ wt2) {
    int i = blockIdx.x * 256 + threadIdx.x;
    if (i < 32768) {
        int r = i >> 14, c = (i >> 7) & 127, k = i & 127;
        wt1[i] = f2b(W1[(r << 14) + (k << 7) + c]);
    } else {
        int j = i - 32768;
        if (j >= 16384) return;
        int r = j >> 13, c = (j >> 7) & 63, k = j & 127;
        wt2[j] = f2b(W2[r * 8192 + k * 64 + c]);
    }
}

// ---------------- CSR build: XCD-partitioned hist + scatter ----------------
__global__ void k_histp(const int* __restrict__ dst, unsigned* __restrict__ cnt,
                        int E, int N, int nchunk) {
    int r = blockIdx.y;
    int part = blockIdx.x & 7, chunk = blockIdx.x >> 3;
    int lo = part * (N / 8), hi = lo + N / 8;
    int per = (E + nchunk - 1) / nchunk;
    int e0 = chunk * per, e1 = min(E, e0 + per);
    const int* dr = dst + (size_t)r * E;
    for (int e = e0 + (int)threadIdx.x; e < e1; e += 256) {
        int d = dr[e];
        if (d >= lo && d < hi) atomicAdd(&cnt[(size_t)r * N + d], 1u);
    }
}

__global__ void k_scatp(const int* __restrict__ src, const int* __restrict__ dst,
                        const unsigned* __restrict__ off, unsigned* __restrict__ cur,
                        int* __restrict__ csr, int E, int N, int nchunk) {
    int r = blockIdx.y;
    int part = blockIdx.x & 7, chunk = blockIdx.x >> 3;
    int lo = part * (N / 8), hi = lo + N / 8;
    int per = (E + nchunk - 1) / nchunk;
    int e0 = chunk * per, e1 = min(E, e0 + per);
    const int* dr = dst + (size_t)r * E;
    const int* sr = src + (size_t)r * E;
    const unsigned* offr = off + (size_t)r * (N + 1);
    for (int e = e0 + (int)threadIdx.x; e < e1; e += 256) {
        int d = dr[e];
        if (d >= lo && d < hi) {
            unsigned pos = atomicAdd(&cur[(size_t)r * N + d], 1u);
            csr[(size_t)r * E + offr[d] + pos] = sr[e];
        }
    }
}

// ---------------- 3-stage exclusive scan over cnt[2][N] -> off[2][N+1] ----------------
#define SCAN_B 1024
__global__ void k_scanA(const unsigned* __restrict__ cnt, unsigned* __restrict__ bsum,
                        int n, int nb) {
    int r = blockIdx.y, b = blockIdx.x;
    int i0 = b * SCAN_B;
    unsigned s = 0;
    for (int t = threadIdx.x; t < SCAN_B; t += 256) {
        int i = i0 + t;
        if (i < n) s += cnt[(size_t)r * n + i];
    }
    __shared__ unsigned red[256];
    red[threadIdx.x] = s; __syncthreads();
    for (int st = 128; st > 0; st >>= 1) {
        if ((int)threadIdx.x < st) red[threadIdx.x] += red[threadIdx.x + st];
        __syncthreads();
    }
    if (threadIdx.x == 0) bsum[r * nb + b] = red[0];
}
__global__ void k_scanB(unsigned* __restrict__ bsum, unsigned* __restrict__ off, int n, int nb) {
    int r = threadIdx.x >> 6, l = threadIdx.x & 63;
    if (r >= 2) return;
    unsigned orig = (l < nb) ? bsum[r * nb + l] : 0u;
    unsigned v = orig;
    for (int st = 1; st < 64; st <<= 1) {
        unsigned t = __shfl_up(v, st);
        if (l >= st) v += t;
    }
    unsigned total = __shfl(v, 63);
    if (l < nb) bsum[r * nb + l] = v - orig;
    if (l == 0) off[(size_t)r * (n + 1) + n] = total;
}
__global__ void k_scanC(const unsigned* __restrict__ cnt, const unsigned* __restrict__ bsum,
                        unsigned* __restrict__ off, int n, int nb) {
    int r = blockIdx.y, b = blockIdx.x;
    int i0 = b * SCAN_B + (int)threadIdx.x * 4;
    unsigned v[4]; unsigned s = 0;
#pragma unroll
    for (int j = 0; j < 4; j++) {
        int i = i0 + j;
        v[j] = (i < n) ? cnt[(size_t)r * n + i] : 0u;
        s += v[j];
    }
    __shared__ unsigned red[256];
    red[threadIdx.x] = s; __syncthreads();
    for (int st = 1; st < 256; st <<= 1) {
        unsigned t = ((int)threadIdx.x >= st) ? red[threadIdx.x - st] : 0u;
        __syncthreads();
        red[threadIdx.x] += t;
        __syncthreads();
    }
    unsigned run = bsum[r * nb + b] + red[threadIdx.x] - s;
#pragma unroll
    for (int j = 0; j < 4; j++) {
        int i = i0 + j;
        if (i < n) off[(size_t)r * (n + 1) + i] = run;
        run += v[j];
    }
}

// ---------------- MFMA GEMM: out[N,M](bf16) = Xb[N,128](bf16) @ Wt[M,128]^T ----------------
// 64 rows/block, 4 waves (16 rows each). XOR-swizzled LDS (G4).
template <int M>
__global__ __launch_bounds__(256) void k_gemm(const unsigned short* __restrict__ Xb,
                                              const unsigned short* __restrict__ Wt,
                                              unsigned short* __restrict__ outp, int N) {
    __shared__ __align__(16) unsigned short xs[64 * 128];
    __shared__ __align__(16) unsigned short ws[M * 128];
    const int tid = threadIdx.x;
    const int row0 = blockIdx.x * 64;
    for (int ch = tid; ch < 64 * 16; ch += 256) {
        int r = ch >> 4, c16 = ch & 15;
        int gr = row0 + r;
        uint4 v = make_uint4(0, 0, 0, 0);
        if (gr < N) v = ((const uint4*)(Xb + (size_t)gr * 128))[c16];
        int byte = r * 256 + ((c16 * 16) ^ ((r & 7) << 4));
        *(uint4*)((char*)xs + byte) = v;
    }
    for (int ch = tid; ch < M * 16; ch += 256) {
        int r = ch >> 4, c16 = ch & 15;
        uint4 v = ((const uint4*)(Wt + (size_t)r * 128))[c16];
        int byte = r * 256 + ((c16 * 16) ^ ((r & 7) << 4));
        *(uint4*)((char*)ws + byte) = v;
    }
    __syncthreads();
    const int w = tid >> 6, l = tid & 63;
    const int ar = w * 16 + (l & 15);
    const int kg = l >> 4;
    bf16x8 a[4];
#pragma unroll
    for (int k4 = 0; k4 < 4; k4++) {
        int byte = ar * 256 + (((kg * 16) + k4 * 64) ^ ((ar & 7) << 4));
        a[k4] = *(const bf16x8*)((const char*)xs + byte);
    }
#pragma unroll
    for (int ct = 0; ct < M / 16; ct++) {
        f32x4 acc = {0.f, 0.f, 0.f, 0.f};
        const int bc = ct * 16 + (l & 15);
#pragma unroll
        for (int k4 = 0; k4 < 4; k4++) {
            int byte = bc * 256 + (((kg * 16) + k4 * 64) ^ ((bc & 7) << 4));
            bf16x8 bfr = *(const bf16x8*)((const char*)ws + byte);
            acc = __builtin_amdgcn_mfma_f32_16x16x32_bf16(a[k4], bfr, acc, 0, 0, 0);
        }
#pragma unroll
        for (int reg = 0; reg < 4; reg++) {
            int gr = row0 + w * 16 + kg * 4 + reg;
            if (gr < N) outp[(size_t)gr * M + ct * 16 + (l & 15)] = f2b(acc[reg]);
        }
    }
}

// ---------------- el/er from bf16 feat ----------------
template <int H, int D>
__global__ void k_eler(const unsigned short* __restrict__ feat, const float* __restrict__ al,
                       const float* __restrict__ ar, float* __restrict__ el,
                       float* __restrict__ er, int N) {
    constexpr int HD = H * D;
    __shared__ float sal[HD], sar[HD];
    for (int i = threadIdx.x; i < HD; i += 256) { sal[i] = al[i]; sar[i] = ar[i]; }
    __syncthreads();
    int n = blockIdx.x * 256 + threadIdx.x;
    if (n >= N) return;
    const uint4* f4 = (const uint4*)(feat + (size_t)n * HD);
    float accl[H], accr[H];
#pragma unroll
    for (int h = 0; h < H; h++) { accl[h] = 0.f; accr[h] = 0.f; }
#pragma unroll
    for (int q = 0; q < HD / 8; q++) {
        uint4 u = f4[q];
        unsigned uu[4] = {u.x, u.y, u.z, u.w};
#pragma unroll
        for (int t = 0; t < 4; t++) {
            int d0 = q * 8 + t * 2;
            int h = d0 / D;
            float f0 = b2f((unsigned short)(uu[t] & 0xffff));
            float f1 = b2f((unsigned short)(uu[t] >> 16));
            accl[h] += f0 * sal[d0] + f1 * sal[d0 + 1];
            accr[h] += f0 * sar[d0] + f1 * sar[d0 + 1];
        }
    }
#pragma unroll
    for (int h = 0; h < H; h++) { el[(size_t)n * H + h] = accl[h]; er[(size_t)n * H + h] = accr[h]; }
}

// ---------------- fused per-node GAT ----------------
template <int H, int D, int ELUF, int OBF>
__global__ __launch_bounds__(256) void k_node_gat(
    const unsigned* __restrict__ off, const int* __restrict__ csr_src,
    const float* __restrict__ el, const float* __restrict__ er,
    const unsigned short* __restrict__ feat0, const unsigned short* __restrict__ feat1,
    const float* __restrict__ bias, void* __restrict__ outp, int N, int E) {
    constexpr int HD = H * D;
    constexpr int F = HD / 64;
    __shared__ float s_w[4][H * 64];
    __shared__ int s_sid[4][64];
    const int wslot = threadIdx.x >> 6;
    const int lane = threadIdx.x & 63;
    const int n = (blockIdx.x * 256 + threadIdx.x) >> 6;
    if (n >= N) return;
    const int c0 = lane * F;
    const int h = c0 / D;

    float res[F];
#pragma unroll
    for (int f = 0; f < F; f++) res[f] = 0.f;

    for (int r = 0; r < 2; r++) {
        const unsigned short* feat = r ? feat1 : feat0;
        const float* elr = el + (size_t)r * N * H;
        const float* ernp = er + (size_t)r * N * H + (size_t)n * H;
        float ern[H];
#pragma unroll
        for (int hh = 0; hh < H; hh++) ern[hh] = ernp[hh];
        const unsigned* offr = off + (size_t)r * (N + 1);
        const int* srcs = csr_src + (size_t)r * E;
        const unsigned o0 = offr[n], o1 = offr[n + 1];

        float ssum[H];
#pragma unroll
        for (int hh = 0; hh < H; hh++) ssum[hh] = 0.f;
        float acc[F];
#pragma unroll
        for (int f = 0; f < F; f++) acc[f] = 0.f;

        for (unsigned base = o0; base < o1; base += 64) {
            const int cnt = (int)min(64u, o1 - base);
            if (lane < cnt) {
                int sv = srcs[base + lane];
                s_sid[wslot][lane] = sv;
                if (H == 4) {
                    float4 e4 = *(const float4*)(elr + (size_t)sv * 4);
                    float v0 = e4.x + ern[0]; v0 = v0 > 0.f ? v0 : 0.2f * v0;
                    float v1 = e4.y + ern[1]; v1 = v1 > 0.f ? v1 : 0.2f * v1;
                    float v2 = e4.z + ern[2]; v2 = v2 > 0.f ? v2 : 0.2f * v2;
                    float v3 = e4.w + ern[3]; v3 = v3 > 0.f ? v3 : 0.2f * v3;
                    float w0 = __expf(v0), w1 = __expf(v1), w2 = __expf(v2), w3 = __expf(v3);
                    s_w[wslot][0 * 64 + lane] = w0; ssum[0] += w0;
                    s_w[wslot][1 * 64 + lane] = w1; ssum[1] += w1;
                    s_w[wslot][2 * 64 + lane] = w2; ssum[2] += w2;
                    s_w[wslot][3 * 64 + lane] = w3; ssum[3] += w3;
                } else {
                    float v = elr[sv] + ern[0]; v = v > 0.f ? v : 0.2f * v;
                    float w0 = __expf(v);
                    s_w[wslot][lane] = w0; ssum[0] += w0;
                }
            }
            asm volatile("s_waitcnt lgkmcnt(0)" ::: "memory");
#pragma unroll 4
            for (int j = 0; j < cnt; j++) {
                int sv = s_sid[wslot][j];
                float wv = s_w[wslot][h * 64 + j];
                if (F == 2) {
                    unsigned u = ((const unsigned*)(feat + (size_t)sv * HD))[lane];
                    acc[0] += wv * b2f((unsigned short)(u & 0xffff));
                    acc[1] += wv * b2f((unsigned short)(u >> 16));
                } else {
                    acc[0] += wv * b2f(feat[(size_t)sv * HD + lane]);
                }
            }
        }
#pragma unroll
        for (int hh = 0; hh < H; hh++) {
            float v = ssum[hh];
#pragma unroll
            for (int o = 32; o > 0; o >>= 1) v += __shfl_xor(v, o);
            ssum[hh] = v;
        }
        float s = ssum[h];
        if (s > 0.f) {
            float inv = 1.f / s;
#pragma unroll
            for (int f = 0; f < F; f++) res[f] += acc[f] * inv;
        }
    }
    if (OBF && F == 2) {
        float v0 = res[0] + bias[c0] + bias[HD + c0];
        float v1 = res[1] + bias[c0 + 1] + bias[HD + c0 + 1];
        if (ELUF) { v0 = v0 > 0.f ? v0 : expm1f(v0); v1 = v1 > 0.f ? v1 : expm1f(v1); }
        ((unsigned*)outp)[((size_t)n * HD + c0) / 2] = f2b(v0) | ((unsigned)f2b(v1) << 16);
    } else {
#pragma unroll
        for (int f = 0; f < F; f++) {
            int c = c0 + f;
            float v = res[f] + bias[c] + bias[HD + c];
            if (ELUF) v = v > 0.f ? v : expm1f(v);
            if (OBF) ((unsigned short*)outp)[(size_t)n * HD + c] = f2b(v);
            else ((float*)outp)[(size_t)n * HD + c] = v;
        }
    }
}

// ---------------- launch ----------------
extern "C" void kernel_launch(void* const* d_in, const int* in_sizes, int n_in,
                              void* d_out, int out_size, void* d_ws, size_t ws_size,
                              hipStream_t stream) {
    const float* x   = (const float*)d_in[0];
    const float* W1  = (const float*)d_in[1];
    const float* al1 = (const float*)d_in[2];
    const float* ar1 = (const float*)d_in[3];
    const float* b1  = (const float*)d_in[4];
    const float* W2  = (const float*)d_in[5];
    const float* al2 = (const float*)d_in[6];
    const float* ar2 = (const float*)d_in[7];
    const float* b2  = (const float*)d_in[8];
    const int* src   = (const int*)d_in[9];
    const int* dst   = (const int*)d_in[10];

    const int N = in_sizes[0] / 128;
    const int E = in_sizes[9] / 2;
    float* out = (float*)d_out;

    char* w = (char*)d_ws;
    unsigned short* xb    = (unsigned short*)w; w += (size_t)N * 128 * 2;
    unsigned short* featA = (unsigned short*)w; w += (size_t)N * 128 * 2;
    unsigned short* featB = (unsigned short*)w; w += (size_t)N * 128 * 2;
    unsigned short* h1b   = (unsigned short*)w; w += (size_t)N * 128 * 2;
    unsigned short* wt1   = (unsigned short*)w; w += (size_t)2 * 128 * 128 * 2;
    unsigned short* wt2   = (unsigned short*)w; w += (size_t)2 * 64 * 128 * 2;
    float* el      = (float*)w; w += (size_t)2 * N * 4 * 4;
    float* er      = (float*)w; w += (size_t)2 * N * 4 * 4;
    unsigned* cnt  = (unsigned*)w; w += (size_t)2 * N * 4;
    unsigned* off  = (unsigned*)w; w += (size_t)2 * (N + 1) * 4;
    unsigned* bsum = (unsigned*)w; w += 2 * 64 * 4;
    int* csr_src   = (int*)w; w += (size_t)2 * E * 4;

    auto cdiv = [](long long a, long long b) { return (int)((a + b - 1) / b); };
    const int NB = cdiv(N, SCAN_B);
    const int NCH = 256;

    // prep
    k_prepx<<<cdiv((long long)N * 16, 256), 256, 0, stream>>>(x, xb, N * 16);
    k_prepw<<<cdiv(49152, 256), 256, 0, stream>>>(W1, W2, wt1, wt2);

    // CSR build
    k_set_u32<<<cdiv(2LL * N, 256), 256, 0, stream>>>(cnt, 0u, 2 * N);
    {
        dim3 g(NCH * 8, 2);
        k_histp<<<g, 256, 0, stream>>>(dst, cnt, E, N, NCH);
    }
    { dim3 g(NB, 2); k_scanA<<<g, 256, 0, stream>>>(cnt, bsum, N, NB); }
    k_scanB<<<1, 128, 0, stream>>>(bsum, off, N, NB);
    { dim3 g(NB, 2); k_scanC<<<g, 256, 0, stream>>>(cnt, bsum, off, N, NB); }
    k_set_u32<<<cdiv(2LL * N, 256), 256, 0, stream>>>(cnt, 0u, 2 * N);
    {
        dim3 g(NCH * 8, 2);
        k_scatp<<<g, 256, 0, stream>>>(src, dst, off, cnt, csr_src, E, N, NCH);
    }

    // ---- layer 1: H=4, D=32 ----
    for (int r = 0; r < 2; r++) {
        unsigned short* feat = r ? featB : featA;
        k_gemm<128><<<cdiv(N, 64), 256, 0, stream>>>(xb, wt1 + (size_t)r * 128 * 128, feat, N);
        k_eler<4, 32><<<cdiv(N, 256), 256, 0, stream>>>(feat, al1 + r * 128, ar1 + r * 128,
                                                        el + (size_t)r * N * 4, er + (size_t)r * N * 4, N);
    }
    k_node_gat<4, 32, 1, 1><<<cdiv(N, 4), 256, 0, stream>>>(off, csr_src, el, er, featA, featB, b1, h1b, N, E);

    // ---- layer 2: H=1, D=64 ----
    for (int r = 0; r < 2; r++) {
        unsigned short* feat = r ? featB : featA;
        k_gemm<64><<<cdiv(N, 64), 256, 0, stream>>>(h1b, wt2 + (size_t)r * 64 * 128, feat, N);
        k_eler<1, 64><<<cdiv(N, 256), 256, 0, stream>>>(feat, al2 + r * 64, ar2 + r * 64,
                                                        el + (size_t)r * N, er + (size_t)r * N, N);
    }
    k_node_gat<1, 64, 0, 0><<<cdiv(N, 4), 256, 0, stream>>>(off, csr_src, el, er, featA, featB, b2, out, N, E);
}

// Round 5
// 334.289 us; speedup vs baseline: 15.0307x; 1.0437x over previous
//
#include <hip/hip_runtime.h>
#include <hip/hip_bf16.h>
#include <math.h>

using bf16x8 = __attribute__((ext_vector_type(8))) short;
using f32x4  = __attribute__((ext_vector_type(4))) float;

__device__ __forceinline__ float b2f(unsigned short u) {
    return __uint_as_float(((unsigned)u) << 16);
}
__device__ __forceinline__ unsigned short f2b(float f) {
    unsigned u = __float_as_uint(f);
    return (unsigned short)((u + 0x7fff + ((u >> 16) & 1)) >> 16);
}

__global__ void k_set_u32(unsigned* __restrict__ p, unsigned v, int n) {
    int i = blockIdx.x * 256 + threadIdx.x;
    if (i < n) p[i] = v;
}

// ---------------- bf16 prep ----------------
__global__ void k_prepx(const float* __restrict__ x, unsigned short* __restrict__ xb, int n8) {
    int i = blockIdx.x * 256 + threadIdx.x;
    if (i >= n8) return;
    float4 a = ((const float4*)x)[i * 2], b = ((const float4*)x)[i * 2 + 1];
    uint4 o;
    o.x = f2b(a.x) | ((unsigned)f2b(a.y) << 16);
    o.y = f2b(a.z) | ((unsigned)f2b(a.w) << 16);
    o.z = f2b(b.x) | ((unsigned)f2b(b.y) << 16);
    o.w = f2b(b.z) | ((unsigned)f2b(b.w) << 16);
    ((uint4*)xb)[i] = o;
}

// Wt1[r][c][k] = W1[r][k][c]  (2x128x128);  Wt2[r][c][k] = W2[r][k][c] (2x64x128)
__global__ void k_prepw(const float* __restrict__ W1, const float* __restrict__ W2,
                        unsigned short* __restrict__ wt1, unsigned short* __restrict__ wt2) {
    int i = blockIdx.x * 256 + threadIdx.x;
    if (i < 32768) {
        int r = i >> 14, c = (i >> 7) & 127, k = i & 127;
        wt1[i] = f2b(W1[(r << 14) + (k << 7) + c]);
    } else {
        int j = i - 32768;
        if (j >= 16384) return;
        int r = j >> 13, c = (j >> 7) & 63, k = j & 127;
        wt2[j] = f2b(W2[r * 8192 + k * 64 + c]);
    }
}

// ---------------- CSR build: XCD-partitioned hist + scatter ----------------
__global__ void k_histp(const int* __restrict__ dst, unsigned* __restrict__ cnt,
                        int E, int N, int nchunk) {
    int r = blockIdx.y;
    int part = blockIdx.x & 7, chunk = blockIdx.x >> 3;
    int lo = part * (N / 8), hi = lo + N / 8;
    int per = (E + nchunk - 1) / nchunk;
    int e0 = chunk * per, e1 = min(E, e0 + per);
    const int* dr = dst + (size_t)r * E;
    for (int e = e0 + (int)threadIdx.x; e < e1; e += 256) {
        int d = dr[e];
        if (d >= lo && d < hi) atomicAdd(&cnt[(size_t)r * N + d], 1u);
    }
}

__global__ void k_scatp(const int* __restrict__ src, const int* __restrict__ dst,
                        const unsigned* __restrict__ off, unsigned* __restrict__ cur,
                        int* __restrict__ csr, int E, int N, int nchunk) {
    int r = blockIdx.y;
    int part = blockIdx.x & 7, chunk = blockIdx.x >> 3;
    int lo = part * (N / 8), hi = lo + N / 8;
    int per = (E + nchunk - 1) / nchunk;
    int e0 = chunk * per, e1 = min(E, e0 + per);
    const int* dr = dst + (size_t)r * E;
    const int* sr = src + (size_t)r * E;
    const unsigned* offr = off + (size_t)r * (N + 1);
    for (int e = e0 + (int)threadIdx.x; e < e1; e += 256) {
        int d = dr[e];
        if (d >= lo && d < hi) {
            unsigned pos = atomicAdd(&cur[(size_t)r * N + d], 1u);
            csr[(size_t)r * E + offr[d] + pos] = sr[e];
        }
    }
}

// ---------------- 3-stage exclusive scan over cnt[2][N] -> off[2][N+1] ----------------
#define SCAN_B 1024
__global__ void k_scanA(const unsigned* __restrict__ cnt, unsigned* __restrict__ bsum,
                        int n, int nb) {
    int r = blockIdx.y, b = blockIdx.x;
    int i0 = b * SCAN_B;
    unsigned s = 0;
    for (int t = threadIdx.x; t < SCAN_B; t += 256) {
        int i = i0 + t;
        if (i < n) s += cnt[(size_t)r * n + i];
    }
    __shared__ unsigned red[256];
    red[threadIdx.x] = s; __syncthreads();
    for (int st = 128; st > 0; st >>= 1) {
        if ((int)threadIdx.x < st) red[threadIdx.x] += red[threadIdx.x + st];
        __syncthreads();
    }
    if (threadIdx.x == 0) bsum[r * nb + b] = red[0];
}
__global__ void k_scanB(unsigned* __restrict__ bsum, unsigned* __restrict__ off, int n, int nb) {
    int r = threadIdx.x >> 6, l = threadIdx.x & 63;
    if (r >= 2) return;
    unsigned orig = (l < nb) ? bsum[r * nb + l] : 0u;
    unsigned v = orig;
    for (int st = 1; st < 64; st <<= 1) {
        unsigned t = __shfl_up(v, st);
        if (l >= st) v += t;
    }
    unsigned total = __shfl(v, 63);
    if (l < nb) bsum[r * nb + l] = v - orig;
    if (l == 0) off[(size_t)r * (n + 1) + n] = total;
}
__global__ void k_scanC(const unsigned* __restrict__ cnt, const unsigned* __restrict__ bsum,
                        unsigned* __restrict__ off, int n, int nb) {
    int r = blockIdx.y, b = blockIdx.x;
    int i0 = b * SCAN_B + (int)threadIdx.x * 4;
    unsigned v[4]; unsigned s = 0;
#pragma unroll
    for (int j = 0; j < 4; j++) {
        int i = i0 + j;
        v[j] = (i < n) ? cnt[(size_t)r * n + i] : 0u;
        s += v[j];
    }
    __shared__ unsigned red[256];
    red[threadIdx.x] = s; __syncthreads();
    for (int st = 1; st < 256; st <<= 1) {
        unsigned t = ((int)threadIdx.x >= st) ? red[threadIdx.x - st] : 0u;
        __syncthreads();
        red[threadIdx.x] += t;
        __syncthreads();
    }
    unsigned run = bsum[r * nb + b] + red[threadIdx.x] - s;
#pragma unroll
    for (int j = 0; j < 4; j++) {
        int i = i0 + j;
        if (i < n) off[(size_t)r * (n + 1) + i] = run;
        run += v[j];
    }
}

// ---------------- MFMA GEMM + fused el/er ----------------
// out[r][N,M](bf16) = Xb[N,128] @ Wt[r][M,128]^T ; el/er[r][N,H] fused.
// blockIdx.y = relation. 64 rows/block, 4 waves (16 rows each).
template <int M, int H>
__global__ __launch_bounds__(256) void k_gemm(const unsigned short* __restrict__ Xb,
                                              const unsigned short* __restrict__ Wt0,
                                              const float* __restrict__ alv,
                                              const float* __restrict__ arv,
                                              unsigned short* __restrict__ feat0,
                                              float* __restrict__ el, float* __restrict__ er,
                                              int N) {
    constexpr int D = M / H;
    const int r = blockIdx.y;
    const unsigned short* Wt = Wt0 + (size_t)r * M * 128;
    unsigned short* outp = feat0 + (size_t)r * N * M;
    float* elr = el + (size_t)r * N * H;
    float* err = er + (size_t)r * N * H;

    __shared__ __align__(16) unsigned short xs[64 * 128];
    __shared__ __align__(16) unsigned short ws[M * 128];
    const int tid = threadIdx.x;
    const int row0 = blockIdx.x * 64;
    for (int ch = tid; ch < 64 * 16; ch += 256) {
        int rr = ch >> 4, c16 = ch & 15;
        int gr = row0 + rr;
        uint4 v = make_uint4(0, 0, 0, 0);
        if (gr < N) v = ((const uint4*)(Xb + (size_t)gr * 128))[c16];
        int byte = rr * 256 + ((c16 * 16) ^ ((rr & 7) << 4));
        *(uint4*)((char*)xs + byte) = v;
    }
    for (int ch = tid; ch < M * 16; ch += 256) {
        int rr = ch >> 4, c16 = ch & 15;
        uint4 v = ((const uint4*)(Wt + (size_t)rr * 128))[c16];
        int byte = rr * 256 + ((c16 * 16) ^ ((rr & 7) << 4));
        *(uint4*)((char*)ws + byte) = v;
    }
    __syncthreads();
    const int w = tid >> 6, l = tid & 63;
    const int sub = l & 15;
    const int ar_ = w * 16 + sub;
    const int kg = l >> 4;
    bf16x8 a[4];
#pragma unroll
    for (int k4 = 0; k4 < 4; k4++) {
        int byte = ar_ * 256 + (((kg * 16) + k4 * 64) ^ ((ar_ & 7) << 4));
        a[k4] = *(const bf16x8*)((const char*)xs + byte);
    }
    float alr[M / 16], arr[M / 16];
#pragma unroll
    for (int ct = 0; ct < M / 16; ct++) {
        alr[ct] = alv[(size_t)r * M + ct * 16 + sub];
        arr[ct] = arv[(size_t)r * M + ct * 16 + sub];
    }
    float pel[H][4], per[H][4];
#pragma unroll
    for (int h = 0; h < H; h++)
#pragma unroll
        for (int q = 0; q < 4; q++) { pel[h][q] = 0.f; per[h][q] = 0.f; }

#pragma unroll
    for (int ct = 0; ct < M / 16; ct++) {
        f32x4 acc = {0.f, 0.f, 0.f, 0.f};
        const int bc = ct * 16 + sub;
#pragma unroll
        for (int k4 = 0; k4 < 4; k4++) {
            int byte = bc * 256 + (((kg * 16) + k4 * 64) ^ ((bc & 7) << 4));
            bf16x8 bfr = *(const bf16x8*)((const char*)ws + byte);
            acc = __builtin_amdgcn_mfma_f32_16x16x32_bf16(a[k4], bfr, acc, 0, 0, 0);
        }
        constexpr int hct0 = 0;  // placate older compilers on constexpr in loop
        const int hct = (ct * 16) / D + hct0;
#pragma unroll
        for (int q = 0; q < 4; q++) {
            pel[hct][q] += acc[q] * alr[ct];
            per[hct][q] += acc[q] * arr[ct];
        }
#pragma unroll
        for (int q = 0; q < 4; q++) {
            int gr = row0 + w * 16 + kg * 4 + q;
            if (gr < N) outp[(size_t)gr * M + ct * 16 + sub] = f2b(acc[q]);
        }
    }
    // reduce pel/per across the 16 lanes of each kg group
#pragma unroll
    for (int h = 0; h < H; h++)
#pragma unroll
        for (int q = 0; q < 4; q++) {
            float v = pel[h][q], u = per[h][q];
#pragma unroll
            for (int o = 8; o > 0; o >>= 1) { v += __shfl_xor(v, o); u += __shfl_xor(u, o); }
            pel[h][q] = v; per[h][q] = u;
        }
#pragma unroll
    for (int h = 0; h < H; h++) {
        if (sub == h) {
#pragma unroll
            for (int q = 0; q < 4; q++) {
                int gr = row0 + w * 16 + kg * 4 + q;
                if (gr < N) { elr[(size_t)gr * H + h] = pel[h][q]; err[(size_t)gr * H + h] = per[h][q]; }
            }
        }
    }
}

// ---------------- fused per-node GAT ----------------
// one wave per node; lane owns F = H*D/64 consecutive output columns.
// s_w layout: [j*H + h] -> conflict-free broadcast reads, float4 writes (H=4).
template <int H, int D, int ELUF, int OBF>
__global__ __launch_bounds__(256) void k_node_gat(
    const unsigned* __restrict__ off, const int* __restrict__ csr_src,
    const float* __restrict__ el, const float* __restrict__ er,
    const unsigned short* __restrict__ feat0, const unsigned short* __restrict__ feat1,
    const float* __restrict__ bias, void* __restrict__ outp, int N, int E) {
    constexpr int HD = H * D;
    constexpr int F = HD / 64;
    __shared__ float s_w[4][H * 64];
    __shared__ int s_sid[4][64];
    const int wslot = threadIdx.x >> 6;
    const int lane = threadIdx.x & 63;
    const int n = (blockIdx.x * 256 + threadIdx.x) >> 6;
    if (n >= N) return;
    const int c0 = lane * F;
    const int h = c0 / D;
    const unsigned laneoff = (F == 2) ? ((unsigned)lane << 2) : ((unsigned)lane << 1);

    float res[F];
#pragma unroll
    for (int f = 0; f < F; f++) res[f] = 0.f;

    for (int r = 0; r < 2; r++) {
        const char* featc = (const char*)(r ? feat1 : feat0);
        const float* elr = el + (size_t)r * N * H;
        const float* ernp = er + (size_t)r * N * H + (size_t)n * H;
        float ern[H];
#pragma unroll
        for (int hh = 0; hh < H; hh++) ern[hh] = ernp[hh];
        const unsigned* offr = off + (size_t)r * (N + 1);
        const int* srcs = csr_src + (size_t)r * E;
        const unsigned o0 = offr[n], o1 = offr[n + 1];

        float ssum[H];
#pragma unroll
        for (int hh = 0; hh < H; hh++) ssum[hh] = 0.f;
        float acc[F];
#pragma unroll
        for (int f = 0; f < F; f++) acc[f] = 0.f;

        for (unsigned base = o0; base < o1; base += 64) {
            const int cnt = (int)min(64u, o1 - base);
            if (lane < cnt) {
                int sv = srcs[base + lane];
                s_sid[wslot][lane] = sv;
                if (H == 4) {
                    float4 e4 = *(const float4*)(elr + (size_t)sv * 4);
                    float v0 = e4.x + ern[0]; v0 = v0 > 0.f ? v0 : 0.2f * v0;
                    float v1 = e4.y + ern[1]; v1 = v1 > 0.f ? v1 : 0.2f * v1;
                    float v2 = e4.z + ern[2]; v2 = v2 > 0.f ? v2 : 0.2f * v2;
                    float v3 = e4.w + ern[3]; v3 = v3 > 0.f ? v3 : 0.2f * v3;
                    float4 wv = make_float4(__expf(v0), __expf(v1), __expf(v2), __expf(v3));
                    *(float4*)&s_w[wslot][lane * 4] = wv;
                    ssum[0] += wv.x; ssum[1] += wv.y; ssum[2] += wv.z; ssum[3] += wv.w;
                } else {
                    float v = elr[sv] + ern[0]; v = v > 0.f ? v : 0.2f * v;
                    float w0 = __expf(v);
                    s_w[wslot][lane] = w0; ssum[0] += w0;
                }
            }
            asm volatile("s_waitcnt lgkmcnt(0)" ::: "memory");
#pragma unroll 8
            for (int j = 0; j < cnt; j++) {
                int sv = s_sid[wslot][j];
                if (F == 2) {
                    float wv = s_w[wslot][j * 4 + h];
                    unsigned u = *(const unsigned*)(featc + (((size_t)(unsigned)sv << 8) + laneoff));
                    acc[0] += wv * __uint_as_float(u << 16);
                    acc[1] += wv * __uint_as_float(u & 0xffff0000u);
                } else {
                    float wv = s_w[wslot][j];
                    unsigned short us = *(const unsigned short*)(featc + (((size_t)(unsigned)sv << 7) + laneoff));
                    acc[0] += wv * b2f(us);
                }
            }
        }
#pragma unroll
        for (int hh = 0; hh < H; hh++) {
            float v = ssum[hh];
#pragma unroll
            for (int o = 32; o > 0; o >>= 1) v += __shfl_xor(v, o);
            ssum[hh] = v;
        }
        float s = ssum[h];
        if (s > 0.f) {
            float inv = 1.f / s;
#pragma unroll
            for (int f = 0; f < F; f++) res[f] += acc[f] * inv;
        }
    }
    if (OBF && F == 2) {
        float v0 = res[0] + bias[c0] + bias[HD + c0];
        float v1 = res[1] + bias[c0 + 1] + bias[HD + c0 + 1];
        if (ELUF) { v0 = v0 > 0.f ? v0 : expm1f(v0); v1 = v1 > 0.f ? v1 : expm1f(v1); }
        ((unsigned*)outp)[((size_t)n * HD + c0) / 2] = f2b(v0) | ((unsigned)f2b(v1) << 16);
    } else {
#pragma unroll
        for (int f = 0; f < F; f++) {
            int c = c0 + f;
            float v = res[f] + bias[c] + bias[HD + c];
            if (ELUF) v = v > 0.f ? v : expm1f(v);
            if (OBF) ((unsigned short*)outp)[(size_t)n * HD + c] = f2b(v);
            else ((float*)outp)[(size_t)n * HD + c] = v;
        }
    }
}

// ---------------- launch ----------------
extern "C" void kernel_launch(void* const* d_in, const int* in_sizes, int n_in,
                              void* d_out, int out_size, void* d_ws, size_t ws_size,
                              hipStream_t stream) {
    const float* x   = (const float*)d_in[0];
    const float* W1  = (const float*)d_in[1];
    const float* al1 = (const float*)d_in[2];
    const float* ar1 = (const float*)d_in[3];
    const float* b1  = (const float*)d_in[4];
    const float* W2  = (const float*)d_in[5];
    const float* al2 = (const float*)d_in[6];
    const float* ar2 = (const float*)d_in[7];
    const float* b2  = (const float*)d_in[8];
    const int* src   = (const int*)d_in[9];
    const int* dst   = (const int*)d_in[10];

    const int N = in_sizes[0] / 128;
    const int E = in_sizes[9] / 2;
    float* out = (float*)d_out;

    char* w = (char*)d_ws;
    unsigned short* xb   = (unsigned short*)w; w += (size_t)N * 128 * 2;
    unsigned short* feat = (unsigned short*)w; w += (size_t)2 * N * 128 * 2;  // [2][N][M]
    unsigned short* h1b  = (unsigned short*)w; w += (size_t)N * 128 * 2;
    unsigned short* wt1  = (unsigned short*)w; w += (size_t)2 * 128 * 128 * 2;
    unsigned short* wt2  = (unsigned short*)w; w += (size_t)2 * 64 * 128 * 2;
    float* el      = (float*)w; w += (size_t)2 * N * 4 * 4;
    float* er      = (float*)w; w += (size_t)2 * N * 4 * 4;
    unsigned* cnt  = (unsigned*)w; w += (size_t)2 * N * 4;
    unsigned* off  = (unsigned*)w; w += (size_t)2 * (N + 1) * 4;
    unsigned* bsum = (unsigned*)w; w += 2 * 64 * 4;
    int* csr_src   = (int*)w; w += (size_t)2 * E * 4;

    auto cdiv = [](long long a, long long b) { return (int)((a + b - 1) / b); };
    const int NB = cdiv(N, SCAN_B);
    const int NCH = 256;

    // prep
    k_prepx<<<cdiv((long long)N * 16, 256), 256, 0, stream>>>(x, xb, N * 16);
    k_prepw<<<cdiv(49152, 256), 256, 0, stream>>>(W1, W2, wt1, wt2);

    // CSR build
    k_set_u32<<<cdiv(2LL * N, 256), 256, 0, stream>>>(cnt, 0u, 2 * N);
    { dim3 g(NCH * 8, 2); k_histp<<<g, 256, 0, stream>>>(dst, cnt, E, N, NCH); }
    { dim3 g(NB, 2); k_scanA<<<g, 256, 0, stream>>>(cnt, bsum, N, NB); }
    k_scanB<<<1, 128, 0, stream>>>(bsum, off, N, NB);
    { dim3 g(NB, 2); k_scanC<<<g, 256, 0, stream>>>(cnt, bsum, off, N, NB); }
    k_set_u32<<<cdiv(2LL * N, 256), 256, 0, stream>>>(cnt, 0u, 2 * N);
    { dim3 g(NCH * 8, 2); k_scatp<<<g, 256, 0, stream>>>(src, dst, off, cnt, csr_src, E, N, NCH); }

    // ---- layer 1: H=4, D=32, M=128 ----
    { dim3 g(cdiv(N, 64), 2);
      k_gemm<128, 4><<<g, 256, 0, stream>>>(xb, wt1, al1, ar1, feat, el, er, N); }
    k_node_gat<4, 32, 1, 1><<<cdiv(N, 4), 256, 0, stream>>>(off, csr_src, el, er,
        feat, feat + (size_t)N * 128, b1, h1b, N, E);

    // ---- layer 2: H=1, D=64, M=64 ----
    { dim3 g(cdiv(N, 64), 2);
      k_gemm<64, 1><<<g, 256, 0, stream>>>(h1b, wt2, al2, ar2, feat, el, er, N); }
    k_node_gat<1, 64, 0, 0><<<cdiv(N, 4), 256, 0, stream>>>(off, csr_src, el, er,
        feat, feat + (size_t)N * 64, b2, out, N, E);
}

// Round 6
// 300.467 us; speedup vs baseline: 16.7226x; 1.1126x over previous
//
#include <hip/hip_runtime.h>
#include <hip/hip_bf16.h>
#include <math.h>

using bf16x8 = __attribute__((ext_vector_type(8))) short;
using f32x4  = __attribute__((ext_vector_type(4))) float;

#define NCH 32  // edge chunks per partition (E divisible by NCH*4)

__device__ __forceinline__ float b2f(unsigned short u) {
    return __uint_as_float(((unsigned)u) << 16);
}
__device__ __forceinline__ unsigned short f2b(float f) {
    unsigned u = __float_as_uint(f);
    return (unsigned short)((u + 0x7fff + ((u >> 16) & 1)) >> 16);
}

// ---------------- fused prep: x->bf16, W->bf16 transposed, zero cnt ----------------
__global__ void k_prep(const float* __restrict__ x, unsigned short* __restrict__ xb, int n8,
                       const float* __restrict__ W1, const float* __restrict__ W2,
                       unsigned short* __restrict__ wt1, unsigned short* __restrict__ wt2,
                       unsigned* __restrict__ cnt, int ncnt, int nbx, int nbw) {
    int bid = blockIdx.x;
    if (bid < nbx) {
        int i = bid * 256 + threadIdx.x;
        if (i >= n8) return;
        float4 a = ((const float4*)x)[i * 2], b = ((const float4*)x)[i * 2 + 1];
        uint4 o;
        o.x = f2b(a.x) | ((unsigned)f2b(a.y) << 16);
        o.y = f2b(a.z) | ((unsigned)f2b(a.w) << 16);
        o.z = f2b(b.x) | ((unsigned)f2b(b.y) << 16);
        o.w = f2b(b.z) | ((unsigned)f2b(b.w) << 16);
        ((uint4*)xb)[i] = o;
    } else if (bid < nbx + nbw) {
        int i = (bid - nbx) * 256 + threadIdx.x;
        if (i < 32768) {
            int r = i >> 14, c = (i >> 7) & 127, k = i & 127;
            wt1[i] = f2b(W1[(r << 14) + (k << 7) + c]);
        } else {
            int j = i - 32768;
            if (j >= 16384) return;
            int r = j >> 13, c = (j >> 7) & 63, k = j & 127;
            wt2[j] = f2b(W2[r * 8192 + k * 64 + c]);
        }
    } else {
        int i = (bid - nbx - nbw) * 256 + threadIdx.x;
        if (i < ncnt) cnt[i] = 0u;
    }
}

// ---------------- histogram: XCD-partitioned, vectorized ----------------
__global__ void k_histp(const int* __restrict__ dst, unsigned* __restrict__ cnt, int E, int N) {
    const int part = blockIdx.x & 7, chunk = blockIdx.x >> 3;
    const int r = blockIdx.y;
    const int lo = part * (N / 8), hi = lo + N / 8;
    const int per = E / NCH;
    const int e0 = chunk * per, e1 = e0 + per;
    const int* dr = dst + (size_t)r * E;
    unsigned* cr = cnt + (size_t)r * N;
    for (int e = e0 + (int)threadIdx.x * 4; e < e1; e += 1024) {
        int4 d4 = *(const int4*)(dr + e);
        if (d4.x >= lo && d4.x < hi) atomicAdd(&cr[d4.x], 1u);
        if (d4.y >= lo && d4.y < hi) atomicAdd(&cr[d4.y], 1u);
        if (d4.z >= lo && d4.z < hi) atomicAdd(&cr[d4.z], 1u);
        if (d4.w >= lo && d4.w < hi) atomicAdd(&cr[d4.w], 1u);
    }
}

// ---------------- 3-stage exclusive scan: cnt[2][N] -> off[2][N+1]; cnt becomes cursor ----------------
#define SCAN_B 1024
__global__ void k_scanA(const unsigned* __restrict__ cnt, unsigned* __restrict__ bsum,
                        int n, int nb) {
    int r = blockIdx.y, b = blockIdx.x;
    int i0 = b * SCAN_B;
    unsigned s = 0;
    for (int t = threadIdx.x; t < SCAN_B; t += 256) {
        int i = i0 + t;
        if (i < n) s += cnt[(size_t)r * n + i];
    }
    __shared__ unsigned red[256];
    red[threadIdx.x] = s; __syncthreads();
    for (int st = 128; st > 0; st >>= 1) {
        if ((int)threadIdx.x < st) red[threadIdx.x] += red[threadIdx.x + st];
        __syncthreads();
    }
    if (threadIdx.x == 0) bsum[r * nb + b] = red[0];
}
__global__ void k_scanB(unsigned* __restrict__ bsum, unsigned* __restrict__ off, int n, int nb) {
    int r = threadIdx.x >> 6, l = threadIdx.x & 63;
    if (r >= 2) return;
    unsigned orig = (l < nb) ? bsum[r * nb + l] : 0u;
    unsigned v = orig;
    for (int st = 1; st < 64; st <<= 1) {
        unsigned t = __shfl_up(v, st);
        if (l >= st) v += t;
    }
    unsigned total = __shfl(v, 63);
    if (l < nb) bsum[r * nb + l] = v - orig;
    if (l == 0) off[(size_t)r * (n + 1) + n] = total;
}
__global__ void k_scanC(unsigned* __restrict__ cnt, const unsigned* __restrict__ bsum,
                        unsigned* __restrict__ off, int n, int nb) {
    int r = blockIdx.y, b = blockIdx.x;
    int i0 = b * SCAN_B + (int)threadIdx.x * 4;
    unsigned v[4]; unsigned s = 0;
#pragma unroll
    for (int j = 0; j < 4; j++) {
        int i = i0 + j;
        v[j] = (i < n) ? cnt[(size_t)r * n + i] : 0u;
        s += v[j];
    }
    __shared__ unsigned red[256];
    red[threadIdx.x] = s; __syncthreads();
    for (int st = 1; st < 256; st <<= 1) {
        unsigned t = ((int)threadIdx.x >= st) ? red[threadIdx.x - st] : 0u;
        __syncthreads();
        red[threadIdx.x] += t;
        __syncthreads();
    }
    unsigned run = bsum[r * nb + b] + red[threadIdx.x] - s;
#pragma unroll
    for (int j = 0; j < 4; j++) {
        int i = i0 + j;
        if (i < n) {
            off[(size_t)r * (n + 1) + i] = run;
            cnt[(size_t)r * n + i] = run;  // cursor = start slot (absolute)
        }
        run += v[j];
    }
}

// ---------------- scatter body (uses cursor in cnt) ----------------
__device__ __forceinline__ void scat_body(int bid, const int* __restrict__ src,
                                          const int* __restrict__ dst, unsigned* __restrict__ cur,
                                          int* __restrict__ csr, int E, int N) {
    const int part = bid & 7;
    const int q = bid >> 3;
    const int r = q & 1, chunk = q >> 1;
    const int lo = part * (N / 8), hi = lo + N / 8;
    const int per = E / NCH;
    const int e0 = chunk * per, e1 = e0 + per;
    const int* dr = dst + (size_t)r * E;
    const int* sr = src + (size_t)r * E;
    unsigned* curr = cur + (size_t)r * N;
    int* csrr = csr + (size_t)r * E;
    for (int e = e0 + (int)threadIdx.x * 4; e < e1; e += 1024) {
        int4 d4 = *(const int4*)(dr + e);
        bool m0 = (d4.x >= lo) & (d4.x < hi);
        bool m1 = (d4.y >= lo) & (d4.y < hi);
        bool m2 = (d4.z >= lo) & (d4.z < hi);
        bool m3 = (d4.w >= lo) & (d4.w < hi);
        if (m0 | m1 | m2 | m3) {
            int4 s4 = *(const int4*)(sr + e);
            if (m0) { unsigned p = atomicAdd(&curr[d4.x], 1u); csrr[p] = s4.x; }
            if (m1) { unsigned p = atomicAdd(&curr[d4.y], 1u); csrr[p] = s4.y; }
            if (m2) { unsigned p = atomicAdd(&curr[d4.z], 1u); csrr[p] = s4.z; }
            if (m3) { unsigned p = atomicAdd(&curr[d4.w], 1u); csrr[p] = s4.w; }
        }
    }
}

// ---------------- MFMA GEMM body + fused el/er ----------------
template <int M, int H>
__device__ __forceinline__ void gemm_body(int xblk, int r,
        const unsigned short* __restrict__ Xb, const unsigned short* __restrict__ Wt0,
        const float* __restrict__ alv, const float* __restrict__ arv,
        unsigned short* __restrict__ feat0, float* __restrict__ el, float* __restrict__ er,
        int N, unsigned short* xs, unsigned short* ws) {
    constexpr int D = M / H;
    const unsigned short* Wt = Wt0 + (size_t)r * M * 128;
    unsigned short* outp = feat0 + (size_t)r * N * M;
    float* elr = el + (size_t)r * N * H;
    float* err = er + (size_t)r * N * H;
    const int tid = threadIdx.x;
    const int row0 = xblk * 64;
    for (int ch = tid; ch < 64 * 16; ch += 256) {
        int rr = ch >> 4, c16 = ch & 15;
        int gr = row0 + rr;
        uint4 v = make_uint4(0, 0, 0, 0);
        if (gr < N) v = ((const uint4*)(Xb + (size_t)gr * 128))[c16];
        int byte = rr * 256 + ((c16 * 16) ^ ((rr & 7) << 4));
        *(uint4*)((char*)xs + byte) = v;
    }
    for (int ch = tid; ch < M * 16; ch += 256) {
        int rr = ch >> 4, c16 = ch & 15;
        uint4 v = ((const uint4*)(Wt + (size_t)rr * 128))[c16];
        int byte = rr * 256 + ((c16 * 16) ^ ((rr & 7) << 4));
        *(uint4*)((char*)ws + byte) = v;
    }
    __syncthreads();
    const int w = tid >> 6, l = tid & 63;
    const int sub = l & 15;
    const int ar_ = w * 16 + sub;
    const int kg = l >> 4;
    bf16x8 a[4];
#pragma unroll
    for (int k4 = 0; k4 < 4; k4++) {
        int byte = ar_ * 256 + (((kg * 16) + k4 * 64) ^ ((ar_ & 7) << 4));
        a[k4] = *(const bf16x8*)((const char*)xs + byte);
    }
    float alr[M / 16], arr[M / 16];
#pragma unroll
    for (int ct = 0; ct < M / 16; ct++) {
        alr[ct] = alv[(size_t)r * M + ct * 16 + sub];
        arr[ct] = arv[(size_t)r * M + ct * 16 + sub];
    }
    float pel[H][4], per[H][4];
#pragma unroll
    for (int h = 0; h < H; h++)
#pragma unroll
        for (int q = 0; q < 4; q++) { pel[h][q] = 0.f; per[h][q] = 0.f; }

#pragma unroll
    for (int ct = 0; ct < M / 16; ct++) {
        f32x4 acc = {0.f, 0.f, 0.f, 0.f};
        const int bc = ct * 16 + sub;
#pragma unroll
        for (int k4 = 0; k4 < 4; k4++) {
            int byte = bc * 256 + (((kg * 16) + k4 * 64) ^ ((bc & 7) << 4));
            bf16x8 bfr = *(const bf16x8*)((const char*)ws + byte);
            acc = __builtin_amdgcn_mfma_f32_16x16x32_bf16(a[k4], bfr, acc, 0, 0, 0);
        }
        const int hct = (ct * 16) / D;
#pragma unroll
        for (int q = 0; q < 4; q++) {
            pel[hct][q] += acc[q] * alr[ct];
            per[hct][q] += acc[q] * arr[ct];
        }
#pragma unroll
        for (int q = 0; q < 4; q++) {
            int gr = row0 + w * 16 + kg * 4 + q;
            if (gr < N) outp[(size_t)gr * M + ct * 16 + sub] = f2b(acc[q]);
        }
    }
#pragma unroll
    for (int h = 0; h < H; h++)
#pragma unroll
        for (int q = 0; q < 4; q++) {
            float v = pel[h][q], u = per[h][q];
#pragma unroll
            for (int o = 8; o > 0; o >>= 1) { v += __shfl_xor(v, o); u += __shfl_xor(u, o); }
            pel[h][q] = v; per[h][q] = u;
        }
#pragma unroll
    for (int h = 0; h < H; h++) {
        if (sub == h) {
#pragma unroll
            for (int q = 0; q < 4; q++) {
                int gr = row0 + w * 16 + kg * 4 + q;
                if (gr < N) { elr[(size_t)gr * H + h] = pel[h][q]; err[(size_t)gr * H + h] = per[h][q]; }
            }
        }
    }
}

// ---------------- fused scatter + layer-1 GEMM ----------------
__global__ __launch_bounds__(256) void k_scatgemm(
    const int* __restrict__ src, const int* __restrict__ dst,
    unsigned* __restrict__ cur, int* __restrict__ csr, int E, int N, int scatBlocks,
    const unsigned short* __restrict__ Xb, const unsigned short* __restrict__ Wt0,
    const float* __restrict__ alv, const float* __restrict__ arv,
    unsigned short* __restrict__ feat0, float* __restrict__ el, float* __restrict__ er) {
    __shared__ __align__(16) unsigned short xs[64 * 128];
    __shared__ __align__(16) unsigned short ws[128 * 128];
    int bid = blockIdx.x;
    if (bid < scatBlocks) {
        scat_body(bid, src, dst, cur, csr, E, N);
    } else {
        int g = bid - scatBlocks;
        gemm_body<128, 4>(g >> 1, g & 1, Xb, Wt0, alv, arv, feat0, el, er, N, xs, ws);
    }
}

// ---------------- layer-2 GEMM ----------------
__global__ __launch_bounds__(256) void k_gemm2(
    const unsigned short* __restrict__ Xb, const unsigned short* __restrict__ Wt0,
    const float* __restrict__ alv, const float* __restrict__ arv,
    unsigned short* __restrict__ feat0, float* __restrict__ el, float* __restrict__ er, int N) {
    __shared__ __align__(16) unsigned short xs[64 * 128];
    __shared__ __align__(16) unsigned short ws[64 * 128];
    gemm_body<64, 1>(blockIdx.x, blockIdx.y, Xb, Wt0, alv, arv, feat0, el, er, N, xs, ws);
}

// ---------------- fused per-node GAT ----------------
template <int H, int D, int ELUF, int OBF>
__global__ __launch_bounds__(256) void k_node_gat(
    const unsigned* __restrict__ off, const int* __restrict__ csr_src,
    const float* __restrict__ el, const float* __restrict__ er,
    const unsigned short* __restrict__ feat0, const unsigned short* __restrict__ feat1,
    const float* __restrict__ bias, void* __restrict__ outp, int N, int E) {
    constexpr int HD = H * D;
    constexpr int F = HD / 64;
    __shared__ float s_w[4][H * 64];
    __shared__ int s_sid[4][64];
    const int wslot = threadIdx.x >> 6;
    const int lane = threadIdx.x & 63;
    const int n = (blockIdx.x * 256 + threadIdx.x) >> 6;
    if (n >= N) return;
    const int c0 = lane * F;
    const int h = c0 / D;
    const unsigned laneoff = (F == 2) ? ((unsigned)lane << 2) : ((unsigned)lane << 1);

    float res[F];
#pragma unroll
    for (int f = 0; f < F; f++) res[f] = 0.f;

    for (int r = 0; r < 2; r++) {
        const char* __restrict__ featc = (const char*)(r ? feat1 : feat0);
        const float* elr = el + (size_t)r * N * H;
        const float* ernp = er + (size_t)r * N * H + (size_t)n * H;
        float ern[H];
#pragma unroll
        for (int hh = 0; hh < H; hh++) ern[hh] = ernp[hh];
        const unsigned* offr = off + (size_t)r * (N + 1);
        const int* srcs = csr_src + (size_t)r * E;
        const unsigned o0 = offr[n], o1 = offr[n + 1];

        float ssum[H];
#pragma unroll
        for (int hh = 0; hh < H; hh++) ssum[hh] = 0.f;
        float acc[F];
#pragma unroll
        for (int f = 0; f < F; f++) acc[f] = 0.f;

        for (unsigned base = o0; base < o1; base += 64) {
            const int cnt = (int)min(64u, o1 - base);
            if (lane < cnt) {
                int sv = srcs[base + lane];
                s_sid[wslot][lane] = sv;
                if (H == 4) {
                    float4 e4 = *(const float4*)(elr + (size_t)sv * 4);
                    float v0 = e4.x + ern[0]; v0 = v0 > 0.f ? v0 : 0.2f * v0;
                    float v1 = e4.y + ern[1]; v1 = v1 > 0.f ? v1 : 0.2f * v1;
                    float v2 = e4.z + ern[2]; v2 = v2 > 0.f ? v2 : 0.2f * v2;
                    float v3 = e4.w + ern[3]; v3 = v3 > 0.f ? v3 : 0.2f * v3;
                    float4 wv = make_float4(__expf(v0), __expf(v1), __expf(v2), __expf(v3));
                    *(float4*)&s_w[wslot][lane * 4] = wv;
                    ssum[0] += wv.x; ssum[1] += wv.y; ssum[2] += wv.z; ssum[3] += wv.w;
                } else {
                    float v = elr[sv] + ern[0]; v = v > 0.f ? v : 0.2f * v;
                    float w0 = __expf(v);
                    s_w[wslot][lane] = w0; ssum[0] += w0;
                }
            }
            asm volatile("s_waitcnt lgkmcnt(0)" ::: "memory");
#pragma unroll 8
            for (int j = 0; j < cnt; j++) {
                unsigned sv = (unsigned)s_sid[wslot][j];
                if (F == 2) {
                    float wv = s_w[wslot][j * 4 + h];
                    unsigned u = *(const unsigned*)(featc + ((sv << 8) + laneoff));
                    acc[0] += wv * __uint_as_float(u << 16);
                    acc[1] += wv * __uint_as_float(u & 0xffff0000u);
                } else {
                    float wv = s_w[wslot][j];
                    unsigned short us = *(const unsigned short*)(featc + ((sv << 7) + laneoff));
                    acc[0] += wv * b2f(us);
                }
            }
        }
#pragma unroll
        for (int hh = 0; hh < H; hh++) {
            float v = ssum[hh];
#pragma unroll
            for (int o = 32; o > 0; o >>= 1) v += __shfl_xor(v, o);
            ssum[hh] = v;
        }
        float s = ssum[h];
        if (s > 0.f) {
            float inv = 1.f / s;
#pragma unroll
            for (int f = 0; f < F; f++) res[f] += acc[f] * inv;
        }
    }
    if (OBF && F == 2) {
        float v0 = res[0] + bias[c0] + bias[HD + c0];
        float v1 = res[1] + bias[c0 + 1] + bias[HD + c0 + 1];
        if (ELUF) { v0 = v0 > 0.f ? v0 : expm1f(v0); v1 = v1 > 0.f ? v1 : expm1f(v1); }
        ((unsigned*)outp)[((size_t)n * HD + c0) / 2] = f2b(v0) | ((unsigned)f2b(v1) << 16);
    } else {
#pragma unroll
        for (int f = 0; f < F; f++) {
            int c = c0 + f;
            float v = res[f] + bias[c] + bias[HD + c];
            if (ELUF) v = v > 0.f ? v : expm1f(v);
            if (OBF) ((unsigned short*)outp)[(size_t)n * HD + c] = f2b(v);
            else ((float*)outp)[(size_t)n * HD + c] = v;
        }
    }
}

// ---------------- launch ----------------
extern "C" void kernel_launch(void* const* d_in, const int* in_sizes, int n_in,
                              void* d_out, int out_size, void* d_ws, size_t ws_size,
                              hipStream_t stream) {
    const float* x   = (const float*)d_in[0];
    const float* W1  = (const float*)d_in[1];
    const float* al1 = (const float*)d_in[2];
    const float* ar1 = (const float*)d_in[3];
    const float* b1  = (const float*)d_in[4];
    const float* W2  = (const float*)d_in[5];
    const float* al2 = (const float*)d_in[6];
    const float* ar2 = (const float*)d_in[7];
    const float* b2  = (const float*)d_in[8];
    const int* src   = (const int*)d_in[9];
    const int* dst   = (const int*)d_in[10];

    const int N = in_sizes[0] / 128;
    const int E = in_sizes[9] / 2;
    float* out = (float*)d_out;

    char* w = (char*)d_ws;
    unsigned short* xb   = (unsigned short*)w; w += (size_t)N * 128 * 2;
    unsigned short* feat = (unsigned short*)w; w += (size_t)2 * N * 128 * 2;  // [2][N][M]
    unsigned short* h1b  = (unsigned short*)w; w += (size_t)N * 128 * 2;
    unsigned short* wt1  = (unsigned short*)w; w += (size_t)2 * 128 * 128 * 2;
    unsigned short* wt2  = (unsigned short*)w; w += (size_t)2 * 64 * 128 * 2;
    float* el      = (float*)w; w += (size_t)2 * N * 4 * 4;
    float* er      = (float*)w; w += (size_t)2 * N * 4 * 4;
    unsigned* cnt  = (unsigned*)w; w += (size_t)2 * N * 4;   // counts -> cursor
    unsigned* off  = (unsigned*)w; w += (size_t)2 * (N + 1) * 4;
    unsigned* bsum = (unsigned*)w; w += 2 * 64 * 4;
    int* csr_src   = (int*)w; w += (size_t)2 * E * 4;

    auto cdiv = [](long long a, long long b) { return (int)((a + b - 1) / b); };
    const int NB = cdiv(N, SCAN_B);

    // ---- fused prep: prepx + prepw + zero cnt ----
    const int nbx = cdiv((long long)N * 16, 256);         // 3125
    const int nbw = cdiv(49152, 256);                     // 192
    const int nbz = cdiv(2LL * N, 256);                   // 391
    k_prep<<<nbx + nbw + nbz, 256, 0, stream>>>(x, xb, N * 16, W1, W2, wt1, wt2, cnt, 2 * N, nbx, nbw);

    // ---- CSR build ----
    { dim3 g(NCH * 8, 2); k_histp<<<g, 256, 0, stream>>>(dst, cnt, E, N); }
    { dim3 g(NB, 2); k_scanA<<<g, 256, 0, stream>>>(cnt, bsum, N, NB); }
    k_scanB<<<1, 128, 0, stream>>>(bsum, off, N, NB);
    { dim3 g(NB, 2); k_scanC<<<g, 256, 0, stream>>>(cnt, bsum, off, N, NB); }

    // ---- fused scatter + layer-1 GEMM (independent work) ----
    const int scatBlocks = NCH * 8 * 2;                   // 512
    const int gemmBlocks = cdiv(N, 64) * 2;
    k_scatgemm<<<scatBlocks + gemmBlocks, 256, 0, stream>>>(
        src, dst, cnt, csr_src, E, N, scatBlocks, xb, wt1, al1, ar1, feat, el, er);

    // ---- layer 1 aggregate ----
    k_node_gat<4, 32, 1, 1><<<cdiv(N, 4), 256, 0, stream>>>(off, csr_src, el, er,
        feat, feat + (size_t)N * 128, b1, h1b, N, E);

    // ---- layer 2 ----
    { dim3 g(cdiv(N, 64), 2);
      k_gemm2<<<g, 256, 0, stream>>>(h1b, wt2, al2, ar2, feat, el, er, N); }
    k_node_gat<1, 64, 0, 0><<<cdiv(N, 4), 256, 0, stream>>>(off, csr_src, el, er,
        feat, feat + (size_t)N * 64, b2, out, N, E);
}